// Round 5
// baseline (6376.250 us; speedup 1.0000x reference)
//
#include <hip/hip_runtime.h>
#include <math.h>

// Model_13348758356240 — R5: depth-4 (full-iteration) W-prefetch pipeline in the
// MFMA GEMM; k_len multiples of 128; gates S=9. Fallback path unchanged.

typedef __attribute__((ext_vector_type(8))) short bf16x8;
typedef __attribute__((ext_vector_type(4))) float f32x4;

#define B_ 128
#define L_ 49
#define D_ 2048
#define H_ 2048
#define E_ 512
#define KA_ 512
#define V_ 10000
#define T_ 20
#define ED_ 2560
#define KT_ 4608
#define H4_ 8192
#define VP_ 10112

__device__ __forceinline__ void split1(float x, short* hi, short* lo){
  unsigned u = __float_as_uint(x);
  *hi = (short)(u >> 16);
  float r = x - __uint_as_float(u & 0xffff0000u);
  *lo = (short)(__float_as_uint(r) >> 16);
}
__device__ __forceinline__ void split8(float4 a, float4 b, bf16x8& h, bf16x8& l){
  float xs[8] = {a.x,a.y,a.z,a.w,b.x,b.y,b.z,b.w};
#pragma unroll
  for (int i=0;i<8;++i){
    unsigned u = __float_as_uint(xs[i]);
    h[i] = (short)(u>>16);
    float r = xs[i] - __uint_as_float(u & 0xffff0000u);
    l[i] = (short)(__float_as_uint(r)>>16);
  }
}

#define MFMA16(d,a,b,c) d = __builtin_amdgcn_mfma_f32_16x16x32_bf16(a,b,c,0,0,0)

// ============ R5 GEMM: Cp = A @ W^T (K-slice), 4-stage W prefetch ============
// A planes: bf16 [Mtot][lda]; W planes: bf16 [Np][ldw] (pad rows zeroed).
// Wave: 128M x 32N. Block: 4 waves (128N). Grid (nb, S, mb). k_len % 128 == 0.
// Each W stage is consumed one full 128-k iteration after its load is issued
// (~4 sub-steps = ~900+ cyc of MFMA/A-load cover for the HBM W stream).
__global__ __launch_bounds__(256, 2)
void gemm_ws(const short* __restrict__ Ah, const short* __restrict__ Al, int lda,
             const short* __restrict__ Wh, const short* __restrict__ Wl, int ldw,
             float* __restrict__ Cp, int Mtot, int Np, int k_len)
{
  const int tid = threadIdx.x;
  const int wid = tid >> 6, lane = tid & 63;
  const int lr = lane & 15, lg = lane >> 4;
  const int m0 = blockIdx.z * 128;
  const int nw = blockIdx.x * 128 + wid * 32;
  const int kb = blockIdx.y * k_len;
  const long rA = (long)(nw + lr) * ldw;
  const long rB = (long)(nw + 16 + lr) * ldw;

  f32x4 acc[8][2];
#pragma unroll
  for (int i=0;i<8;++i)
#pragma unroll
    for (int r=0;r<4;++r){ acc[i][0][r]=0.f; acc[i][1][r]=0.f; }

  const int kw = kb + 8*lg;
  bf16x8 W0hA = *(const bf16x8*)(Wh + rA + kw      );
  bf16x8 W0lA = *(const bf16x8*)(Wl + rA + kw      );
  bf16x8 W0hB = *(const bf16x8*)(Wh + rB + kw      );
  bf16x8 W0lB = *(const bf16x8*)(Wl + rB + kw      );
  bf16x8 W1hA = *(const bf16x8*)(Wh + rA + kw + 32 );
  bf16x8 W1lA = *(const bf16x8*)(Wl + rA + kw + 32 );
  bf16x8 W1hB = *(const bf16x8*)(Wh + rB + kw + 32 );
  bf16x8 W1lB = *(const bf16x8*)(Wl + rB + kw + 32 );
  bf16x8 W2hA = *(const bf16x8*)(Wh + rA + kw + 64 );
  bf16x8 W2lA = *(const bf16x8*)(Wl + rA + kw + 64 );
  bf16x8 W2hB = *(const bf16x8*)(Wh + rB + kw + 64 );
  bf16x8 W2lB = *(const bf16x8*)(Wl + rB + kw + 64 );
  bf16x8 W3hA = *(const bf16x8*)(Wh + rA + kw + 96 );
  bf16x8 W3lA = *(const bf16x8*)(Wl + rA + kw + 96 );
  bf16x8 W3hB = *(const bf16x8*)(Wh + rB + kw + 96 );
  bf16x8 W3lB = *(const bf16x8*)(Wl + rB + kw + 96 );

  const long ab = (long)(m0 + lr) * lda + kb + 8*lg;

#define SUBSTEP(KOFF, WHA, WLA, WHB, WLB)                                    \
  {                                                                          \
    bf16x8 ah[8], al[8];                                                     \
    _Pragma("unroll")                                                        \
    for (int mt=0; mt<8; ++mt){                                              \
      const long o = ab + (long)mt*16*lda + kk + (KOFF);                     \
      ah[mt] = *(const bf16x8*)(Ah + o);                                     \
      al[mt] = *(const bf16x8*)(Al + o);                                     \
    }                                                                        \
    _Pragma("unroll")                                                        \
    for (int mt=0; mt<8; ++mt){                                              \
      MFMA16(acc[mt][0], ah[mt], WHA, acc[mt][0]);                           \
      MFMA16(acc[mt][1], ah[mt], WHB, acc[mt][1]);                           \
      MFMA16(acc[mt][0], ah[mt], WLA, acc[mt][0]);                           \
      MFMA16(acc[mt][1], ah[mt], WLB, acc[mt][1]);                           \
      MFMA16(acc[mt][0], al[mt], WHA, acc[mt][0]);                           \
      MFMA16(acc[mt][1], al[mt], WHB, acc[mt][1]);                           \
    }                                                                        \
    WHA = *(const bf16x8*)(Wh + rA + kpre + (KOFF));                         \
    WLA = *(const bf16x8*)(Wl + rA + kpre + (KOFF));                         \
    WHB = *(const bf16x8*)(Wh + rB + kpre + (KOFF));                         \
    WLB = *(const bf16x8*)(Wl + rB + kpre + (KOFF));                         \
  }

  for (int kk = 0; kk < k_len; kk += 128) {
    // last iteration: wrap prefetch to slice start (valid addr, never consumed)
    const int kpre = ((kk + 128 < k_len) ? (kb + kk + 128) : kb) + 8*lg;
    SUBSTEP(0,  W0hA, W0lA, W0hB, W0lB)
    SUBSTEP(32, W1hA, W1lA, W1hB, W1lB)
    SUBSTEP(64, W2hA, W2lA, W2hB, W2lB)
    SUBSTEP(96, W3hA, W3lA, W3hB, W3lB)
  }
#undef SUBSTEP

  const long srow = (long)blockIdx.y * Mtot + m0;
#pragma unroll
  for (int mt=0; mt<8; ++mt)
#pragma unroll
    for (int nt=0; nt<2; ++nt){
      const int col = nw + nt*16 + lr;
#pragma unroll
      for (int r=0; r<4; ++r)
        Cp[(srow + mt*16 + 4*lg + r)*Np + col] = acc[mt][nt][r];
    }
}

// ============ fallback GEMM: fp32 W, on-the-fly split ============
template<bool AF32>
__global__ __launch_bounds__(256)
void gemm_mfma(const void* Ahv, const void* Alv, int lda,
               const float* __restrict__ W1, int ldw1,
               const float* __restrict__ W2, int ldw2, int ksplit,
               float* __restrict__ Cp, int Mtot, int Np, int Nvalid, int k_len)
{
  const int tid = threadIdx.x;
  const int wid = tid >> 6, lane = tid & 63;
  const int lr = lane & 15, lg = lane >> 4;
  const int m0 = blockIdx.z * 128;
  const int nw = blockIdx.x * 128 + wid * 32;
  const int kb = blockIdx.y * k_len;

  int rowA = nw + lr;       if (rowA >= Nvalid) rowA = Nvalid - 1;
  int rowB = nw + 16 + lr;  if (rowB >= Nvalid) rowB = Nvalid - 1;

  f32x4 acc[8][2];
#pragma unroll
  for (int i=0;i<8;++i)
#pragma unroll
    for (int r=0;r<4;++r){ acc[i][0][r]=0.f; acc[i][1][r]=0.f; }

  for (int kk = 0; kk < k_len; kk += 32) {
    const int kg = kb + kk;
    const float *pA, *pB;
    if (W2 && kg >= ksplit) {
      pA = W2 + (long)rowA*ldw2 + (kg - ksplit) + 8*lg;
      pB = W2 + (long)rowB*ldw2 + (kg - ksplit) + 8*lg;
    } else {
      pA = W1 + (long)rowA*ldw1 + kg + 8*lg;
      pB = W1 + (long)rowB*ldw1 + kg + 8*lg;
    }
    bf16x8 whA, wlA, whB, wlB;
    split8(*(const float4*)pA, *(const float4*)(pA+4), whA, wlA);
    split8(*(const float4*)pB, *(const float4*)(pB+4), whB, wlB);

    bf16x8 ah[8], al[8];
    if constexpr (AF32) {
      const float* Af = (const float*)Ahv;
#pragma unroll
      for (int mt=0; mt<8; ++mt){
        const float* ap = Af + (long)(m0 + mt*16 + lr)*lda + kg + 8*lg;
        split8(*(const float4*)ap, *(const float4*)(ap+4), ah[mt], al[mt]);
      }
    } else {
      const short* Ah = (const short*)Ahv;
      const short* Al = (const short*)Alv;
#pragma unroll
      for (int mt=0; mt<8; ++mt){
        const long off = (long)(m0 + mt*16 + lr)*lda + kg + 8*lg;
        ah[mt] = *(const bf16x8*)(Ah + off);
        al[mt] = *(const bf16x8*)(Al + off);
      }
    }
#pragma unroll
    for (int mt=0; mt<8; ++mt){
      MFMA16(acc[mt][0], ah[mt], whA, acc[mt][0]);
      MFMA16(acc[mt][1], ah[mt], whB, acc[mt][1]);
      MFMA16(acc[mt][0], ah[mt], wlA, acc[mt][0]);
      MFMA16(acc[mt][1], ah[mt], wlB, acc[mt][1]);
      MFMA16(acc[mt][0], al[mt], whA, acc[mt][0]);
      MFMA16(acc[mt][1], al[mt], whB, acc[mt][1]);
    }
  }

  const long srow = (long)blockIdx.y * Mtot + m0;
#pragma unroll
  for (int mt=0; mt<8; ++mt)
#pragma unroll
    for (int nt=0; nt<2; ++nt){
      const int col = nw + nt*16 + lr;
#pragma unroll
      for (int r=0; r<4; ++r)
        Cp[(srow + mt*16 + 4*lg + r)*Np + col] = acc[mt][nt][r];
    }
}

// ============ prep kernels ============
__global__ __launch_bounds__(256)
void split_nt_k(const float* __restrict__ W, int Nv, int Kin,
                short* __restrict__ Wh, short* __restrict__ Wl, int ldo, int ko)
{
  const int n = blockIdx.y;
  const int k = blockIdx.x * 1024 + threadIdx.x * 4;
  if (k >= Kin) return;
  short4 hv, lv;
  if (n < Nv) {
    const float4 v = *(const float4*)&W[(long)n*Kin + k];
    split1(v.x, &hv.x, &lv.x); split1(v.y, &hv.y, &lv.y);
    split1(v.z, &hv.z, &lv.z); split1(v.w, &hv.w, &lv.w);
  } else {
    hv.x=hv.y=hv.z=hv.w=0; lv.x=lv.y=lv.z=lv.w=0;
  }
  *(short4*)&Wh[(long)n*ldo + ko + k] = hv;
  *(short4*)&Wl[(long)n*ldo + ko + k] = lv;
}

__global__ __launch_bounds__(256)
void split_t_k(const float* __restrict__ in, int K, int N,
               short* __restrict__ Oh, short* __restrict__ Ol)
{
  __shared__ float t[64][65];
  const int tid = threadIdx.x;
  const int c0 = blockIdx.x * 64, r0 = blockIdx.y * 64;
  const int lx = tid & 63, ly = tid >> 6;
#pragma unroll
  for (int i = 0; i < 16; ++i)
    t[ly + 4*i][lx] = in[(long)(r0 + ly + 4*i) * N + c0 + lx];
  __syncthreads();
#pragma unroll
  for (int i = 0; i < 16; ++i) {
    short hh, ll;
    split1(t[lx][ly + 4*i], &hh, &ll);
    const long o = (long)(c0 + ly + 4*i) * K + r0 + lx;
    Oh[o] = hh; Ol[o] = ll;
  }
}

__global__ __launch_bounds__(256)
void split_plane_k(const float* __restrict__ in, long n,
                   short* __restrict__ oh, short* __restrict__ ol)
{
  const long i = ((long)blockIdx.x * 256 + threadIdx.x) * 4;
  if (i >= n) return;
  const float4 v = *(const float4*)&in[i];
  short4 hv, lv;
  split1(v.x, &hv.x, &lv.x); split1(v.y, &hv.y, &lv.y);
  split1(v.z, &hv.z, &lv.z); split1(v.w, &hv.w, &lv.w);
  *(short4*)&oh[i] = hv;
  *(short4*)&ol[i] = lv;
}

__global__ __launch_bounds__(256)
void transpose_f32(const float* __restrict__ in, int R, int C, float* __restrict__ out)
{
  __shared__ float t[64][65];
  const int tid = threadIdx.x;
  const int c0 = blockIdx.x * 64, r0 = blockIdx.y * 64;
  const int lx = tid & 63, ly = tid >> 6;
#pragma unroll
  for (int i = 0; i < 16; ++i)
    t[ly + 4*i][lx] = in[(long)(r0 + ly + 4*i) * C + c0 + lx];
  __syncthreads();
#pragma unroll
  for (int i = 0; i < 16; ++i)
    out[(long)(c0 + ly + 4*i) * R + r0 + lx] = t[lx][ly + 4*i];
}

__global__ void reduce_sp_k(const float4* __restrict__ p, float4* __restrict__ sp)
{
  const long i = (long)blockIdx.x * 256 + threadIdx.x;   // 802,816 float4s
  const long s = 802816;
  float4 a = p[i], b = p[i+s], c = p[i+2*s], d = p[i+3*s];
  float4 r;
  r.x = (a.x+b.x)+(c.x+d.x); r.y = (a.y+b.y)+(c.y+d.y);
  r.z = (a.z+b.z)+(c.z+d.z); r.w = (a.w+b.w)+(c.w+d.w);
  sp[i] = r;
}

// ============ step kernels ============
__global__ void init_tok_k(int* tok) {
  if (threadIdx.x < B_) tok[threadIdx.x] = 1; // START_IDX
}

__global__ __launch_bounds__(256)
void reduce_tanh_k(const float* __restrict__ gp, int S, float* __restrict__ out,
                   short* __restrict__ ohi, short* __restrict__ olo)
{
  const int idx = blockIdx.x * 256 + threadIdx.x;
  float s = 0.f;
  for (int sl = 0; sl < S; ++sl) s += gp[(long)sl * (B_*H_) + idx];
  s = tanhf(s);
  out[idx] = s;
  if (ohi) split1(s, &ohi[idx], &olo[idx]);
}

__global__ void gather_xh_k(const float* __restrict__ embed, const float* __restrict__ global_,
                            const short* __restrict__ h_hi, const short* __restrict__ h_lo,
                            const int* __restrict__ tok,
                            short* __restrict__ xh_hi, short* __restrict__ xh_lo)
{
  const int b = blockIdx.x, tid = threadIdx.x;
  const int tk = tok[b];
  short* rh = xh_hi + (long)b * KT_;
  short* rl = xh_lo + (long)b * KT_;
  const float* e = embed + (long)tk * E_;
  for (int i = tid; i < E_; i += 256) split1(e[i], &rh[i], &rl[i]);
  for (int i = tid; i < D_; i += 256) split1(global_[(long)b * D_ + i], &rh[E_ + i], &rl[E_ + i]);
  for (int i = tid; i < H_; i += 256) { rh[ED_ + i] = h_hi[(long)b * H_ + i]; rl[ED_ + i] = h_lo[(long)b * H_ + i]; }
}

template<int S>
__global__ __launch_bounds__(256)
void lstm_reduce_k(const float* __restrict__ gp, const float* __restrict__ b_ih,
                   const float* __restrict__ b_hh, float* __restrict__ h, float* __restrict__ m,
                   short* __restrict__ h_hi, short* __restrict__ h_lo)
{
  const int idx = blockIdx.x * 256 + threadIdx.x;
  const int b = idx >> 11, n = idx & (H_ - 1);
  float g[4];
#pragma unroll
  for (int j = 0; j < 4; ++j) {
    float s = b_ih[j*H_ + n] + b_hh[j*H_ + n];
#pragma unroll
    for (int sl = 0; sl < S; ++sl) s += gp[((long)sl * B_ + b) * H4_ + j*H_ + n];
    g[j] = s;
  }
  const float si = 1.f / (1.f + expf(-g[0]));
  const float sf = 1.f / (1.f + expf(-g[1]));
  const float gg = tanhf(g[2]);
  const float so = 1.f / (1.f + expf(-g[3]));
  const float mn = sf * m[idx] + si * gg;
  const float hn = so * tanhf(mn);
  m[idx] = mn; h[idx] = hn;
  split1(hn, &h_hi[idx], &h_lo[idx]);
}

__global__ __launch_bounds__(256)
void attn_k(const float* __restrict__ sp_proj, const float* __restrict__ hgp,
            const float* __restrict__ w_h, const float* __restrict__ spatial,
            const float* __restrict__ h,
            short* __restrict__ a_hi, short* __restrict__ a_lo)
{
  const int b = blockIdx.x, half = blockIdx.y, tid = threadIdx.x;
  const int lane = tid & 63, wv = tid >> 6;
  __shared__ float hgs[KA_];
  __shared__ float whs[KA_];
  __shared__ float zs[L_];
  __shared__ float alph[L_];
  for (int i = tid; i < KA_; i += 256) {
    float s = 0.f;
#pragma unroll
    for (int sl = 0; sl < 16; ++sl) s += hgp[((long)sl * B_ + b) * KA_ + i];
    hgs[i] = s; whs[i] = w_h[i];
  }
  __syncthreads();
  for (int l = wv; l < L_; l += 4) {
    const float* sp = sp_proj + ((long)b * L_ + l) * KA_;
    float s = 0.f;
    for (int k = lane; k < KA_; k += 64) s += whs[k] * tanhf(sp[k] + hgs[k]);
#pragma unroll
    for (int off = 32; off > 0; off >>= 1) s += __shfl_down(s, off);
    if (lane == 0) zs[l] = s;
  }
  __syncthreads();
  if (wv == 0) {
    float v = (lane < L_) ? zs[lane] : -INFINITY;
    float mx = v;
#pragma unroll
    for (int off = 32; off > 0; off >>= 1) mx = fmaxf(mx, __shfl_xor(mx, off));
    float e = (lane < L_) ? expf(v - mx) : 0.f;
    float sum = e;
#pragma unroll
    for (int off = 32; off > 0; off >>= 1) sum += __shfl_xor(sum, off);
    if (lane < L_) alph[lane] = e / sum;
  }
  __syncthreads();
  const int d4 = half * 256 + tid;
  const float4* h4 = (const float4*)h;
  const float4* sp4 = (const float4*)spatial;
  float4 acc = h4[(long)b * 512 + d4];
#pragma unroll 7
  for (int l = 0; l < L_; ++l) {
    const float w = alph[l];
    const float4 v = sp4[((long)b * L_ + l) * 512 + d4];
    acc.x = fmaf(w, v.x, acc.x); acc.y = fmaf(w, v.y, acc.y);
    acc.z = fmaf(w, v.z, acc.z); acc.w = fmaf(w, v.w, acc.w);
  }
  short4 hv, lv;
  split1(acc.x, &hv.x, &lv.x); split1(acc.y, &hv.y, &lv.y);
  split1(acc.z, &hv.z, &lv.z); split1(acc.w, &hv.w, &lv.w);
  *(short4*)&a_hi[(long)b * D_ + d4*4] = hv;
  *(short4*)&a_lo[(long)b * D_ + d4*4] = lv;
}

template<int S, bool GATHER>
__global__ __launch_bounds__(256)
void logits_argmax_k(const float* __restrict__ lp, const float* __restrict__ bias,
                     float* __restrict__ outL, int* __restrict__ tok,
                     float* __restrict__ tokout,
                     const float* __restrict__ embed,
                     const short* __restrict__ g_hi, const short* __restrict__ g_lo,
                     const short* __restrict__ h_hi, const short* __restrict__ h_lo,
                     short* __restrict__ xh_hi, short* __restrict__ xh_lo)
{
  const int b = blockIdx.x, tid = threadIdx.x;
  float bv = -INFINITY; int bi = 0x7fffffff;
  for (int j = tid; j < V_; j += 256) {
    float v = bias[j];
#pragma unroll
    for (int sl = 0; sl < S; ++sl) v += lp[((long)sl * B_ + b) * VP_ + j];
    outL[(long)b * (T_*V_) + j] = v;
    if (v > bv) { bv = v; bi = j; }
  }
  __shared__ float sv[256];
  __shared__ int   si[256];
  sv[tid] = bv; si[tid] = bi;
  __syncthreads();
  for (int s = 128; s > 0; s >>= 1) {
    if (tid < s) {
      const float ov = sv[tid + s]; const int oi = si[tid + s];
      if (ov > sv[tid] || (ov == sv[tid] && oi < si[tid])) { sv[tid] = ov; si[tid] = oi; }
    }
    __syncthreads();
  }
  if (tid == 0) { tok[b] = si[0]; tokout[(long)b * T_] = (float)si[0]; }
  if (GATHER) {
    __syncthreads();
    const int tk = si[0];
    short* rh = xh_hi + (long)b * KT_;
    short* rl = xh_lo + (long)b * KT_;
    const float* e = embed + (long)tk * E_;
    for (int i = tid; i < E_; i += 256) split1(e[i], &rh[i], &rl[i]);
    for (int i = tid; i < D_; i += 256) { rh[E_+i] = g_hi[(long)b*D_ + i]; rl[E_+i] = g_lo[(long)b*D_ + i]; }
    for (int i = tid; i < H_; i += 256) { rh[ED_+i] = h_hi[(long)b*H_ + i]; rl[ED_+i] = h_lo[(long)b*H_ + i]; }
  }
}

// ============ host ============
extern "C" void kernel_launch(void* const* d_in, const int* in_sizes, int n_in,
                              void* d_out, int out_size, void* d_ws, size_t ws_size,
                              hipStream_t stream)
{
  const float* spatial  = (const float*)d_in[0];
  const float* global_  = (const float*)d_in[1];
  const float* embed    = (const float*)d_in[2];
  const float* W_ih     = (const float*)d_in[3];
  const float* W_hh     = (const float*)d_in[4];
  const float* b_ih     = (const float*)d_in[5];
  const float* b_hh     = (const float*)d_in[6];
  const float* W_v      = (const float*)d_in[7];
  const float* W_g      = (const float*)d_in[8];
  const float* w_h      = (const float*)d_in[9];
  const float* W_p_w    = (const float*)d_in[10];
  const float* W_p_b    = (const float*)d_in[11];
  const float* W_init_h = (const float*)d_in[12];
  const float* W_init_m = (const float*)d_in[13];
  float* out = (float*)d_out;
  float* tokout = out + (long)B_ * T_ * V_;

  char* base = (char*)d_ws;
  const size_t NEED_PRE = 304087808;
  const size_t NEED_FB  = 62390784;
  if (ws_size < NEED_FB) return;

  if (ws_size >= NEED_PRE) {
    float* sp    = (float*)(base + 0);           // 12,845,056
    float* h     = (float*)(base + 12845056);    //  1,048,576
    float* m     = (float*)(base + 13893632);    //  1,048,576
    short* h_hi  = (short*)(base + 14942208);    //    524,288
    short* h_lo  = (short*)(base + 15466496);
    short* a_hi  = (short*)(base + 15990784);
    short* a_lo  = (short*)(base + 16515072);
    short* xh_hi = (short*)(base + 17039360);    //  1,179,648
    short* xh_lo = (short*)(base + 18219008);
    short* g_hi  = (short*)(base + 19398656);    //    524,288
    short* g_lo  = (short*)(base + 19922944);
    int*   tok   = (int*)  (base + 20447232);    //        512
    float* arena = (float*)(base + 20447744);    // 41,418,752
    short* Wcat_hi = (short*)(base + 61866496);  // 75,497,472
    short* Wcat_lo = (short*)(base + 137363968);
    short* Wp_hi   = (short*)(base + 212861440); // 41,418,752
    short* Wp_lo   = (short*)(base + 254280192);
    short* WvT_hi  = (short*)(base + 295698944); //  2,097,152
    short* WvT_lo  = (short*)(base + 297796096);
    short* WgT_hi  = (short*)(base + 299893248);
    short* WgT_lo  = (short*)(base + 301990400);

    init_tok_k<<<1, 128, 0, stream>>>(tok);

    // sp = spatial @ W_v : planes, S=4 (k_len 512), reduce
    split_t_k<<<dim3(KA_/64, D_/64), 256, 0, stream>>>(W_v, D_, KA_, WvT_hi, WvT_lo);
    short* spA_hi = Wp_hi;
    short* spA_lo = (short*)((char*)Wp_hi + 25690112);
    split_plane_k<<<12544, 256, 0, stream>>>(spatial, (long)B_*L_*D_, spA_hi, spA_lo);
    float* sppart = (float*)Wcat_hi;
    gemm_ws<<<dim3(4, 4, 49), 256, 0, stream>>>(
        spA_hi, spA_lo, D_, WvT_hi, WvT_lo, D_, sppart, B_*L_, KA_, 512);
    reduce_sp_k<<<3136, 256, 0, stream>>>((const float4*)sppart, (float4*)sp);

    // weight planes
    split_t_k<<<dim3(KA_/64, H_/64), 256, 0, stream>>>(W_g, H_, KA_, WgT_hi, WgT_lo);
    split_nt_k<<<dim3(3, H4_), 256, 0, stream>>>(W_ih, H4_, ED_, Wcat_hi, Wcat_lo, KT_, 0);
    split_nt_k<<<dim3(2, H4_), 256, 0, stream>>>(W_hh, H4_, H_,  Wcat_hi, Wcat_lo, KT_, ED_);
    split_nt_k<<<dim3(2, VP_), 256, 0, stream>>>(W_p_w, V_, H_,  Wp_hi,   Wp_lo,   H_, 0);
    split_plane_k<<<256, 256, 0, stream>>>(global_, (long)B_*D_, g_hi, g_lo);

    // h0/m0 (k_len 128, S=16)
    {
      short* WTh = (short*)arena;
      short* WTl = (short*)((char*)arena + 8388608);
      float* prt = (float*)((char*)arena + 16777216);
      split_t_k<<<dim3(H_/64, D_/64), 256, 0, stream>>>(W_init_h, D_, H_, WTh, WTl);
      gemm_ws<<<dim3(16, 16, 1), 256, 0, stream>>>(
          g_hi, g_lo, D_, WTh, WTl, D_, prt, B_, H_, 128);
      reduce_tanh_k<<<(B_*H_)/256, 256, 0, stream>>>(prt, 16, h, h_hi, h_lo);
      split_t_k<<<dim3(H_/64, D_/64), 256, 0, stream>>>(W_init_m, D_, H_, WTh, WTl);
      gemm_ws<<<dim3(16, 16, 1), 256, 0, stream>>>(
          g_hi, g_lo, D_, WTh, WTl, D_, prt, B_, H_, 128);
      reduce_tanh_k<<<(B_*H_)/256, 256, 0, stream>>>(prt, 16, m, nullptr, nullptr);
    }

    gather_xh_k<<<B_, 256, 0, stream>>>(embed, global_, h_hi, h_lo, tok, xh_hi, xh_lo);

    for (int t = 0; t < T_; ++t) {
      // gates: S=9, k_len=512 (multiple of 128)
      gemm_ws<<<dim3(64, 9, 1), 256, 0, stream>>>(
          xh_hi, xh_lo, KT_, Wcat_hi, Wcat_lo, KT_, arena, B_, H4_, 512);
      lstm_reduce_k<9><<<(B_*H_)/256, 256, 0, stream>>>(arena, b_ih, b_hh, h, m, h_hi, h_lo);
      // hg: S=16, k_len=128
      gemm_ws<<<dim3(4, 16, 1), 256, 0, stream>>>(
          h_hi, h_lo, H_, WgT_hi, WgT_lo, H_, arena, B_, KA_, 128);
      attn_k<<<dim3(B_, 2), 256, 0, stream>>>(sp, arena, w_h, spatial, h, a_hi, a_lo);
      // logits: S=8, k_len=256
      gemm_ws<<<dim3(79, 8, 1), 256, 0, stream>>>(
          a_hi, a_lo, H_, Wp_hi, Wp_lo, H_, arena, B_, VP_, 256);
      logits_argmax_k<8,true><<<B_, 256, 0, stream>>>(
          arena, W_p_b, out + (long)t * V_, tok, tokout + t,
          embed, g_hi, g_lo, h_hi, h_lo, xh_hi, xh_lo);
    }
  } else {
    // -------- fallback: fp32 weights, on-the-fly split --------
    float* sp    = (float*)(base + 0);
    float* WvTf  = (float*)(base + 12845056);
    float* WgTf  = (float*)(base + 17039360);
    float* h     = (float*)(base + 21233664);
    float* m     = (float*)(base + 22282240);
    short* h_hi  = (short*)(base + 24379392);
    short* h_lo  = (short*)(base + 24903680);
    short* a_hi  = (short*)(base + 25427968);
    short* a_lo  = (short*)(base + 25952256);
    short* xh_hi = (short*)(base + 26476544);
    short* xh_lo = (short*)(base + 27656192);
    int*   tok   = (int*)  (base + 28835840);
    float* arena = (float*)(base + 28836352);

    init_tok_k<<<1, 128, 0, stream>>>(tok);
    transpose_f32<<<dim3(KA_/64, D_/64), 256, 0, stream>>>(W_v, D_, KA_, WvTf);
    gemm_mfma<true><<<dim3(4, 1, 49), 256, 0, stream>>>(
        spatial, nullptr, D_, WvTf, D_, nullptr, 0, 1<<30, sp, B_*L_, KA_, KA_, D_);
    transpose_f32<<<dim3(KA_/64, H_/64), 256, 0, stream>>>(W_g, H_, KA_, WgTf);
    {
      float* WT  = arena;
      float* prt = (float*)((char*)arena + 16777216);
      transpose_f32<<<dim3(H_/64, D_/64), 256, 0, stream>>>(W_init_h, D_, H_, WT);
      gemm_mfma<true><<<dim3(16, 4, 1), 256, 0, stream>>>(
          global_, nullptr, D_, WT, D_, nullptr, 0, 1<<30, prt, B_, H_, H_, 512);
      reduce_tanh_k<<<(B_*H_)/256, 256, 0, stream>>>(prt, 4, h, h_hi, h_lo);
      transpose_f32<<<dim3(H_/64, D_/64), 256, 0, stream>>>(W_init_m, D_, H_, WT);
      gemm_mfma<true><<<dim3(16, 4, 1), 256, 0, stream>>>(
          global_, nullptr, D_, WT, D_, nullptr, 0, 1<<30, prt, B_, H_, H_, 512);
      reduce_tanh_k<<<(B_*H_)/256, 256, 0, stream>>>(prt, 4, m, nullptr, nullptr);
    }
    for (int t = 0; t < T_; ++t) {
      gather_xh_k<<<B_, 256, 0, stream>>>(embed, global_, h_hi, h_lo, tok, xh_hi, xh_lo);
      gemm_mfma<false><<<dim3(64, 8, 1), 256, 0, stream>>>(
          xh_hi, xh_lo, KT_, W_ih, ED_, W_hh, H_, ED_, arena, B_, H4_, H4_, 576);
      lstm_reduce_k<8><<<(B_*H_)/256, 256, 0, stream>>>(arena, b_ih, b_hh, h, m, h_hi, h_lo);
      gemm_mfma<false><<<dim3(4, 16, 1), 256, 0, stream>>>(
          h_hi, h_lo, H_, WgTf, H_, nullptr, 0, 1<<30, arena, B_, KA_, KA_, 128);
      attn_k<<<dim3(B_, 2), 256, 0, stream>>>(sp, arena, w_h, spatial, h, a_hi, a_lo);
      gemm_mfma<false><<<dim3(79, 4, 1), 256, 0, stream>>>(
          a_hi, a_lo, H_, W_p_w, H_, nullptr, 0, 1<<30, arena, B_, VP_, V_, 512);
      logits_argmax_k<4,false><<<B_, 256, 0, stream>>>(
          arena, W_p_b, out + (long)t * V_, tok, tokout + t,
          nullptr, nullptr, nullptr, nullptr, nullptr, nullptr, nullptr);
    }
  }
}

// Round 6
// 5629.037 us; speedup vs baseline: 1.1327x; 1.1327x over previous
//
#include <hip/hip_runtime.h>
#include <math.h>

// Model_13348758356240 — R6: gconst precompute (gates K 4608->2560), big split-K
// grids for occupancy (gates S=20, logits S=16, hg S=32), R4-style depth-2 GEMM.

typedef __attribute__((ext_vector_type(8))) short bf16x8;
typedef __attribute__((ext_vector_type(4))) float f32x4;

#define B_ 128
#define L_ 49
#define D_ 2048
#define H_ 2048
#define E_ 512
#define KA_ 512
#define V_ 10000
#define T_ 20
#define ED_ 2560
#define KT_ 4608
#define KT2_ 2560
#define H4_ 8192
#define VP_ 10112

__device__ __forceinline__ void split1(float x, short* hi, short* lo){
  unsigned u = __float_as_uint(x);
  *hi = (short)(u >> 16);
  float r = x - __uint_as_float(u & 0xffff0000u);
  *lo = (short)(__float_as_uint(r) >> 16);
}
__device__ __forceinline__ void split8(float4 a, float4 b, bf16x8& h, bf16x8& l){
  float xs[8] = {a.x,a.y,a.z,a.w,b.x,b.y,b.z,b.w};
#pragma unroll
  for (int i=0;i<8;++i){
    unsigned u = __float_as_uint(xs[i]);
    h[i] = (short)(u>>16);
    float r = xs[i] - __uint_as_float(u & 0xffff0000u);
    l[i] = (short)(__float_as_uint(r)>>16);
  }
}

#define MFMA16(d,a,b,c) d = __builtin_amdgcn_mfma_f32_16x16x32_bf16(a,b,c,0,0,0)

// ============ GEMM: Cp = A @ W^T (K-slice), depth-2 W prefetch (R4) ============
// A planes: bf16 [Mtot][lda]; W planes: bf16 [Np][ldw] (pad rows zeroed).
// Wave: 128M x 32N. Block: 4 waves (128N). Grid (nb, S, mb). k_len % 64 == 0.
__global__ __launch_bounds__(256)
void gemm_ws(const short* __restrict__ Ah, const short* __restrict__ Al, int lda,
             const short* __restrict__ Wh, const short* __restrict__ Wl, int ldw,
             float* __restrict__ Cp, int Mtot, int Np, int k_len)
{
  const int tid = threadIdx.x;
  const int wid = tid >> 6, lane = tid & 63;
  const int lr = lane & 15, lg = lane >> 4;
  const int m0 = blockIdx.z * 128;
  const int nw = blockIdx.x * 128 + wid * 32;
  const int kb = blockIdx.y * k_len;
  const long rA = (long)(nw + lr) * ldw;
  const long rB = (long)(nw + 16 + lr) * ldw;
  const int kmax = ldw - 8;

  f32x4 acc[8][2];
#pragma unroll
  for (int i=0;i<8;++i)
#pragma unroll
    for (int r=0;r<4;++r){ acc[i][0][r]=0.f; acc[i][1][r]=0.f; }

  const int k0 = kb + 8*lg;
  bf16x8 w0hA = *(const bf16x8*)(Wh + rA + k0);
  bf16x8 w0lA = *(const bf16x8*)(Wl + rA + k0);
  bf16x8 w0hB = *(const bf16x8*)(Wh + rB + k0);
  bf16x8 w0lB = *(const bf16x8*)(Wl + rB + k0);
  const int k1 = k0 + 32;
  bf16x8 w1hA = *(const bf16x8*)(Wh + rA + k1);
  bf16x8 w1lA = *(const bf16x8*)(Wl + rA + k1);
  bf16x8 w1hB = *(const bf16x8*)(Wh + rB + k1);
  bf16x8 w1lB = *(const bf16x8*)(Wl + rB + k1);

  const long ab = (long)(m0 + lr) * lda + kb + 8*lg;

  for (int kk = 0; kk < k_len; kk += 64) {
    {
      bf16x8 ah[8], al[8];
#pragma unroll
      for (int mt=0; mt<8; ++mt){
        const long o = ab + (long)mt*16*lda + kk;
        ah[mt] = *(const bf16x8*)(Ah + o);
        al[mt] = *(const bf16x8*)(Al + o);
      }
#pragma unroll
      for (int mt=0; mt<8; ++mt){
        MFMA16(acc[mt][0], ah[mt], w0hA, acc[mt][0]);
        MFMA16(acc[mt][1], ah[mt], w0hB, acc[mt][1]);
        MFMA16(acc[mt][0], ah[mt], w0lA, acc[mt][0]);
        MFMA16(acc[mt][1], ah[mt], w0lB, acc[mt][1]);
        MFMA16(acc[mt][0], al[mt], w0hA, acc[mt][0]);
        MFMA16(acc[mt][1], al[mt], w0hB, acc[mt][1]);
      }
      int kp = k0 + kk + 64; if (kp > kmax) kp = kmax;
      w0hA = *(const bf16x8*)(Wh + rA + kp);
      w0lA = *(const bf16x8*)(Wl + rA + kp);
      w0hB = *(const bf16x8*)(Wh + rB + kp);
      w0lB = *(const bf16x8*)(Wl + rB + kp);
    }
    {
      bf16x8 ah[8], al[8];
#pragma unroll
      for (int mt=0; mt<8; ++mt){
        const long o = ab + (long)mt*16*lda + kk + 32;
        ah[mt] = *(const bf16x8*)(Ah + o);
        al[mt] = *(const bf16x8*)(Al + o);
      }
#pragma unroll
      for (int mt=0; mt<8; ++mt){
        MFMA16(acc[mt][0], ah[mt], w1hA, acc[mt][0]);
        MFMA16(acc[mt][1], ah[mt], w1hB, acc[mt][1]);
        MFMA16(acc[mt][0], ah[mt], w1lA, acc[mt][0]);
        MFMA16(acc[mt][1], ah[mt], w1lB, acc[mt][1]);
        MFMA16(acc[mt][0], al[mt], w1hA, acc[mt][0]);
        MFMA16(acc[mt][1], al[mt], w1hB, acc[mt][1]);
      }
      int kp = k1 + kk + 64; if (kp > kmax) kp = kmax;
      w1hA = *(const bf16x8*)(Wh + rA + kp);
      w1lA = *(const bf16x8*)(Wl + rA + kp);
      w1hB = *(const bf16x8*)(Wh + rB + kp);
      w1lB = *(const bf16x8*)(Wl + rB + kp);
    }
  }

  const long srow = (long)blockIdx.y * Mtot + m0;
#pragma unroll
  for (int mt=0; mt<8; ++mt)
#pragma unroll
    for (int nt=0; nt<2; ++nt){
      const int col = nw + nt*16 + lr;
#pragma unroll
      for (int r=0; r<4; ++r)
        Cp[(srow + mt*16 + 4*lg + r)*Np + col] = acc[mt][nt][r];
    }
}

// ============ fallback GEMM: fp32 W, on-the-fly split ============
template<bool AF32>
__global__ __launch_bounds__(256)
void gemm_mfma(const void* Ahv, const void* Alv, int lda,
               const float* __restrict__ W1, int ldw1,
               const float* __restrict__ W2, int ldw2, int ksplit,
               float* __restrict__ Cp, int Mtot, int Np, int Nvalid, int k_len)
{
  const int tid = threadIdx.x;
  const int wid = tid >> 6, lane = tid & 63;
  const int lr = lane & 15, lg = lane >> 4;
  const int m0 = blockIdx.z * 128;
  const int nw = blockIdx.x * 128 + wid * 32;
  const int kb = blockIdx.y * k_len;

  int rowA = nw + lr;       if (rowA >= Nvalid) rowA = Nvalid - 1;
  int rowB = nw + 16 + lr;  if (rowB >= Nvalid) rowB = Nvalid - 1;

  f32x4 acc[8][2];
#pragma unroll
  for (int i=0;i<8;++i)
#pragma unroll
    for (int r=0;r<4;++r){ acc[i][0][r]=0.f; acc[i][1][r]=0.f; }

  for (int kk = 0; kk < k_len; kk += 32) {
    const int kg = kb + kk;
    const float *pA, *pB;
    if (W2 && kg >= ksplit) {
      pA = W2 + (long)rowA*ldw2 + (kg - ksplit) + 8*lg;
      pB = W2 + (long)rowB*ldw2 + (kg - ksplit) + 8*lg;
    } else {
      pA = W1 + (long)rowA*ldw1 + kg + 8*lg;
      pB = W1 + (long)rowB*ldw1 + kg + 8*lg;
    }
    bf16x8 whA, wlA, whB, wlB;
    split8(*(const float4*)pA, *(const float4*)(pA+4), whA, wlA);
    split8(*(const float4*)pB, *(const float4*)(pB+4), whB, wlB);

    bf16x8 ah[8], al[8];
    if constexpr (AF32) {
      const float* Af = (const float*)Ahv;
#pragma unroll
      for (int mt=0; mt<8; ++mt){
        const float* ap = Af + (long)(m0 + mt*16 + lr)*lda + kg + 8*lg;
        split8(*(const float4*)ap, *(const float4*)(ap+4), ah[mt], al[mt]);
      }
    } else {
      const short* Ah = (const short*)Ahv;
      const short* Al = (const short*)Alv;
#pragma unroll
      for (int mt=0; mt<8; ++mt){
        const long off = (long)(m0 + mt*16 + lr)*lda + kg + 8*lg;
        ah[mt] = *(const bf16x8*)(Ah + off);
        al[mt] = *(const bf16x8*)(Al + off);
      }
    }
#pragma unroll
    for (int mt=0; mt<8; ++mt){
      MFMA16(acc[mt][0], ah[mt], whA, acc[mt][0]);
      MFMA16(acc[mt][1], ah[mt], whB, acc[mt][1]);
      MFMA16(acc[mt][0], ah[mt], wlA, acc[mt][0]);
      MFMA16(acc[mt][1], ah[mt], wlB, acc[mt][1]);
      MFMA16(acc[mt][0], al[mt], whA, acc[mt][0]);
      MFMA16(acc[mt][1], al[mt], whB, acc[mt][1]);
    }
  }

  const long srow = (long)blockIdx.y * Mtot + m0;
#pragma unroll
  for (int mt=0; mt<8; ++mt)
#pragma unroll
    for (int nt=0; nt<2; ++nt){
      const int col = nw + nt*16 + lr;
#pragma unroll
      for (int r=0; r<4; ++r)
        Cp[(srow + mt*16 + 4*lg + r)*Np + col] = acc[mt][nt][r];
    }
}

// ============ prep kernels ============
// fp32 [n][src_ld] (cols [0,kcount)) -> bf16 planes [n][ldo] at col offset ko
__global__ __launch_bounds__(256)
void split_nt_k(const float* __restrict__ W, int src_ld, int Nv, int kcount,
                short* __restrict__ Wh, short* __restrict__ Wl, int ldo, int ko)
{
  const int n = blockIdx.y;
  const int k = blockIdx.x * 1024 + threadIdx.x * 4;
  if (k >= kcount) return;
  short4 hv, lv;
  if (n < Nv) {
    const float4 v = *(const float4*)&W[(long)n*src_ld + k];
    split1(v.x, &hv.x, &lv.x); split1(v.y, &hv.y, &lv.y);
    split1(v.z, &hv.z, &lv.z); split1(v.w, &hv.w, &lv.w);
  } else {
    hv.x=hv.y=hv.z=hv.w=0; lv.x=lv.y=lv.z=lv.w=0;
  }
  *(short4*)&Wh[(long)n*ldo + ko + k] = hv;
  *(short4*)&Wl[(long)n*ldo + ko + k] = lv;
}

__global__ __launch_bounds__(256)
void split_t_k(const float* __restrict__ in, int K, int N,
               short* __restrict__ Oh, short* __restrict__ Ol)
{
  __shared__ float t[64][65];
  const int tid = threadIdx.x;
  const int c0 = blockIdx.x * 64, r0 = blockIdx.y * 64;
  const int lx = tid & 63, ly = tid >> 6;
#pragma unroll
  for (int i = 0; i < 16; ++i)
    t[ly + 4*i][lx] = in[(long)(r0 + ly + 4*i) * N + c0 + lx];
  __syncthreads();
#pragma unroll
  for (int i = 0; i < 16; ++i) {
    short hh, ll;
    split1(t[lx][ly + 4*i], &hh, &ll);
    const long o = (long)(c0 + ly + 4*i) * K + r0 + lx;
    Oh[o] = hh; Ol[o] = ll;
  }
}

__global__ __launch_bounds__(256)
void split_plane_k(const float* __restrict__ in, long n,
                   short* __restrict__ oh, short* __restrict__ ol)
{
  const long i = ((long)blockIdx.x * 256 + threadIdx.x) * 4;
  if (i >= n) return;
  const float4 v = *(const float4*)&in[i];
  short4 hv, lv;
  split1(v.x, &hv.x, &lv.x); split1(v.y, &hv.y, &lv.y);
  split1(v.z, &hv.z, &lv.z); split1(v.w, &hv.w, &lv.w);
  *(short4*)&oh[i] = hv;
  *(short4*)&ol[i] = lv;
}

__global__ __launch_bounds__(256)
void transpose_f32(const float* __restrict__ in, int R, int C, float* __restrict__ out)
{
  __shared__ float t[64][65];
  const int tid = threadIdx.x;
  const int c0 = blockIdx.x * 64, r0 = blockIdx.y * 64;
  const int lx = tid & 63, ly = tid >> 6;
#pragma unroll
  for (int i = 0; i < 16; ++i)
    t[ly + 4*i][lx] = in[(long)(r0 + ly + 4*i) * C + c0 + lx];
  __syncthreads();
#pragma unroll
  for (int i = 0; i < 16; ++i)
    out[(long)(c0 + ly + 4*i) * R + r0 + lx] = t[lx][ly + 4*i];
}

__global__ void reduce_sp_k(const float4* __restrict__ p, float4* __restrict__ sp)
{
  const long i = (long)blockIdx.x * 256 + threadIdx.x;   // 802,816 float4s
  const long s = 802816;
  float4 a = p[i], b = p[i+s], c = p[i+2*s], d = p[i+3*s];
  float4 r;
  r.x = (a.x+b.x)+(c.x+d.x); r.y = (a.y+b.y)+(c.y+d.y);
  r.z = (a.z+b.z)+(c.z+d.z); r.w = (a.w+b.w)+(c.w+d.w);
  sp[i] = r;
}

// gconst = sum_S partials + b_ih + b_hh   (layout [B][8192])
__global__ __launch_bounds__(256)
void gred_k(const float* __restrict__ prt, const float* __restrict__ b_ih,
            const float* __restrict__ b_hh, float* __restrict__ gconst)
{
  const int idx = blockIdx.x * 256 + threadIdx.x;   // 0..B*H4-1
  const int n = idx & (H4_ - 1);
  float s = b_ih[n] + b_hh[n];
#pragma unroll
  for (int sl = 0; sl < 8; ++sl) s += prt[(long)sl * (B_*H4_) + idx];
  gconst[idx] = s;
}

// ============ step kernels ============
__global__ void init_tok_k(int* tok) {
  if (threadIdx.x < B_) tok[threadIdx.x] = 1; // START_IDX
}

__global__ __launch_bounds__(256)
void reduce_tanh_k(const float* __restrict__ gp, int S, float* __restrict__ out,
                   short* __restrict__ ohi, short* __restrict__ olo)
{
  const int idx = blockIdx.x * 256 + threadIdx.x;
  float s = 0.f;
  for (int sl = 0; sl < S; ++sl) s += gp[(long)sl * (B_*H_) + idx];
  s = tanhf(s);
  out[idx] = s;
  if (ohi) split1(s, &ohi[idx], &olo[idx]);
}

// initial xh2 = [emb(tok) | h] planes (KT2 = 2560)
__global__ void gather_xh2_k(const float* __restrict__ embed,
                             const short* __restrict__ h_hi, const short* __restrict__ h_lo,
                             const int* __restrict__ tok,
                             short* __restrict__ xh_hi, short* __restrict__ xh_lo)
{
  const int b = blockIdx.x, tid = threadIdx.x;
  const int tk = tok[b];
  short* rh = xh_hi + (long)b * KT2_;
  short* rl = xh_lo + (long)b * KT2_;
  const float* e = embed + (long)tk * E_;
  for (int i = tid; i < E_; i += 256) split1(e[i], &rh[i], &rl[i]);
  for (int i = tid; i < H_; i += 256) { rh[E_ + i] = h_hi[(long)b * H_ + i]; rl[E_ + i] = h_lo[(long)b * H_ + i]; }
}

// fallback initial gather (KT_ = 4608 with global_)
__global__ void gather_xh_k(const float* __restrict__ embed, const float* __restrict__ global_,
                            const short* __restrict__ h_hi, const short* __restrict__ h_lo,
                            const int* __restrict__ tok,
                            short* __restrict__ xh_hi, short* __restrict__ xh_lo)
{
  const int b = blockIdx.x, tid = threadIdx.x;
  const int tk = tok[b];
  short* rh = xh_hi + (long)b * KT_;
  short* rl = xh_lo + (long)b * KT_;
  const float* e = embed + (long)tk * E_;
  for (int i = tid; i < E_; i += 256) split1(e[i], &rh[i], &rl[i]);
  for (int i = tid; i < D_; i += 256) split1(global_[(long)b * D_ + i], &rh[E_ + i], &rl[E_ + i]);
  for (int i = tid; i < H_; i += 256) { rh[ED_ + i] = h_hi[(long)b * H_ + i]; rl[ED_ + i] = h_lo[(long)b * H_ + i]; }
}

// reduce gates partials (S) + gconst[b][n] (or biases) + LSTM cell
template<int S>
__global__ __launch_bounds__(256)
void lstm_reduce_k(const float* __restrict__ gp, const float* __restrict__ gconst,
                   const float* __restrict__ b1, const float* __restrict__ b2,
                   float* __restrict__ h, float* __restrict__ m,
                   short* __restrict__ h_hi, short* __restrict__ h_lo)
{
  const int idx = blockIdx.x * 256 + threadIdx.x;
  const int b = idx >> 11, n = idx & (H_ - 1);
  float g[4];
#pragma unroll
  for (int j = 0; j < 4; ++j) {
    float s = gconst ? gconst[(long)b * H4_ + j*H_ + n] : (b1[j*H_ + n] + b2[j*H_ + n]);
#pragma unroll
    for (int sl = 0; sl < S; ++sl) s += gp[((long)sl * B_ + b) * H4_ + j*H_ + n];
    g[j] = s;
  }
  const float si = 1.f / (1.f + expf(-g[0]));
  const float sf = 1.f / (1.f + expf(-g[1]));
  const float gg = tanhf(g[2]);
  const float so = 1.f / (1.f + expf(-g[3]));
  const float mn = sf * m[idx] + si * gg;
  const float hn = so * tanhf(mn);
  m[idx] = mn; h[idx] = hn;
  split1(hn, &h_hi[idx], &h_lo[idx]);
}

template<int SHG>
__global__ __launch_bounds__(256)
void attn_k(const float* __restrict__ sp_proj, const float* __restrict__ hgp,
            const float* __restrict__ w_h, const float* __restrict__ spatial,
            const float* __restrict__ h,
            short* __restrict__ a_hi, short* __restrict__ a_lo)
{
  const int b = blockIdx.x, half = blockIdx.y, tid = threadIdx.x;
  const int lane = tid & 63, wv = tid >> 6;
  __shared__ float hgs[KA_];
  __shared__ float whs[KA_];
  __shared__ float zs[L_];
  __shared__ float alph[L_];
  for (int i = tid; i < KA_; i += 256) {
    float s = 0.f;
#pragma unroll
    for (int sl = 0; sl < SHG; ++sl) s += hgp[((long)sl * B_ + b) * KA_ + i];
    hgs[i] = s; whs[i] = w_h[i];
  }
  __syncthreads();
  for (int l = wv; l < L_; l += 4) {
    const float* sp = sp_proj + ((long)b * L_ + l) * KA_;
    float s = 0.f;
    for (int k = lane; k < KA_; k += 64) s += whs[k] * tanhf(sp[k] + hgs[k]);
#pragma unroll
    for (int off = 32; off > 0; off >>= 1) s += __shfl_down(s, off);
    if (lane == 0) zs[l] = s;
  }
  __syncthreads();
  if (wv == 0) {
    float v = (lane < L_) ? zs[lane] : -INFINITY;
    float mx = v;
#pragma unroll
    for (int off = 32; off > 0; off >>= 1) mx = fmaxf(mx, __shfl_xor(mx, off));
    float e = (lane < L_) ? expf(v - mx) : 0.f;
    float sum = e;
#pragma unroll
    for (int off = 32; off > 0; off >>= 1) sum += __shfl_xor(sum, off);
    if (lane < L_) alph[lane] = e / sum;
  }
  __syncthreads();
  const int d4 = half * 256 + tid;
  const float4* h4 = (const float4*)h;
  const float4* sp4 = (const float4*)spatial;
  float4 acc = h4[(long)b * 512 + d4];
#pragma unroll 7
  for (int l = 0; l < L_; ++l) {
    const float w = alph[l];
    const float4 v = sp4[((long)b * L_ + l) * 512 + d4];
    acc.x = fmaf(w, v.x, acc.x); acc.y = fmaf(w, v.y, acc.y);
    acc.z = fmaf(w, v.z, acc.z); acc.w = fmaf(w, v.w, acc.w);
  }
  short4 hv, lv;
  split1(acc.x, &hv.x, &lv.x); split1(acc.y, &hv.y, &lv.y);
  split1(acc.z, &hv.z, &lv.z); split1(acc.w, &hv.w, &lv.w);
  *(short4*)&a_hi[(long)b * D_ + d4*4] = hv;
  *(short4*)&a_lo[(long)b * D_ + d4*4] = lv;
}

// reduce logits partials (S, padded VP_) + bias -> out, argmax, optional xh2 gather
template<int S, bool GATHER>
__global__ __launch_bounds__(256)
void logits_argmax_k(const float* __restrict__ lp, const float* __restrict__ bias,
                     float* __restrict__ outL, int* __restrict__ tok,
                     float* __restrict__ tokout,
                     const float* __restrict__ embed,
                     const short* __restrict__ h_hi, const short* __restrict__ h_lo,
                     short* __restrict__ xh_hi, short* __restrict__ xh_lo)
{
  const int b = blockIdx.x, tid = threadIdx.x;
  float bv = -INFINITY; int bi = 0x7fffffff;
  for (int j = tid; j < V_; j += 256) {
    float v = bias[j];
#pragma unroll
    for (int sl = 0; sl < S; ++sl) v += lp[((long)sl * B_ + b) * VP_ + j];
    outL[(long)b * (T_*V_) + j] = v;
    if (v > bv) { bv = v; bi = j; }
  }
  __shared__ float sv[256];
  __shared__ int   si[256];
  sv[tid] = bv; si[tid] = bi;
  __syncthreads();
  for (int s = 128; s > 0; s >>= 1) {
    if (tid < s) {
      const float ov = sv[tid + s]; const int oi = si[tid + s];
      if (ov > sv[tid] || (ov == sv[tid] && oi < si[tid])) { sv[tid] = ov; si[tid] = oi; }
    }
    __syncthreads();
  }
  if (tid == 0) { tok[b] = si[0]; tokout[(long)b * T_] = (float)si[0]; }
  if (GATHER) {
    __syncthreads();
    const int tk = si[0];
    short* rh = xh_hi + (long)b * KT2_;
    short* rl = xh_lo + (long)b * KT2_;
    const float* e = embed + (long)tk * E_;
    for (int i = tid; i < E_; i += 256) split1(e[i], &rh[i], &rl[i]);
    for (int i = tid; i < H_; i += 256) { rh[E_+i] = h_hi[(long)b*H_ + i]; rl[E_+i] = h_lo[(long)b*H_ + i]; }
  }
}

// ============ host ============
extern "C" void kernel_launch(void* const* d_in, const int* in_sizes, int n_in,
                              void* d_out, int out_size, void* d_ws, size_t ws_size,
                              hipStream_t stream)
{
  const float* spatial  = (const float*)d_in[0];
  const float* global_  = (const float*)d_in[1];
  const float* embed    = (const float*)d_in[2];
  const float* W_ih     = (const float*)d_in[3];
  const float* W_hh     = (const float*)d_in[4];
  const float* b_ih     = (const float*)d_in[5];
  const float* b_hh     = (const float*)d_in[6];
  const float* W_v      = (const float*)d_in[7];
  const float* W_g      = (const float*)d_in[8];
  const float* w_h      = (const float*)d_in[9];
  const float* W_p_w    = (const float*)d_in[10];
  const float* W_p_b    = (const float*)d_in[11];
  const float* W_init_h = (const float*)d_in[12];
  const float* W_init_m = (const float*)d_in[13];
  float* out = (float*)d_out;
  float* tokout = out + (long)B_ * T_ * V_;

  char* base = (char*)d_ws;
  const size_t NEED_PRE = 282591744;
  const size_t NEED_FB  = 62390784;
  if (ws_size < NEED_FB) return;

  if (ws_size >= NEED_PRE) {
    float* sp      = (float*)(base + 0);           // 12,845,056
    float* h       = (float*)(base + 12845056);    //  1,048,576
    float* m       = (float*)(base + 13893632);    //  1,048,576
    short* h_hi    = (short*)(base + 14942208);    //    524,288
    short* h_lo    = (short*)(base + 15466496);
    short* a_hi    = (short*)(base + 15990784);
    short* a_lo    = (short*)(base + 16515072);
    short* xh_hi   = (short*)(base + 17039360);    //    655,360 (128 x 2560)
    short* xh_lo   = (short*)(base + 17694720);
    short* g_hi    = (short*)(base + 18350080);    //    524,288
    short* g_lo    = (short*)(base + 18874368);
    float* gconst  = (float*)(base + 19398656);    //  4,194,304
    int*   tok     = (int*)  (base + 23592960);    //        512
    float* arena   = (float*)(base + 23593472);    // 83,886,080 (gates S=20 partials)
    short* Wcat_hi = (short*)(base + 107479552);   // 41,943,040 (8192 x 2560)
    short* Wcat_lo = (short*)(base + 149422592);
    short* Wp_hi   = (short*)(base + 191365632);   // 41,418,752 (10112 x 2048)
    short* Wp_lo   = (short*)(base + 232784384);
    short* WvT_hi  = (short*)(base + 274203136);   //  2,097,152
    short* WvT_lo  = (short*)(base + 276300288);
    short* WgT_hi  = (short*)(base + 278397440);
    short* WgT_lo  = (short*)(base + 280494592);

    init_tok_k<<<1, 128, 0, stream>>>(tok);
    split_plane_k<<<256, 256, 0, stream>>>(global_, (long)B_*D_, g_hi, g_lo);

    // ---- sp = spatial @ W_v (S=4), staged in Wp (A planes) + Wcat (partials) ----
    split_t_k<<<dim3(KA_/64, D_/64), 256, 0, stream>>>(W_v, D_, KA_, WvT_hi, WvT_lo);
    short* spA_hi = Wp_hi;
    short* spA_lo = (short*)((char*)Wp_hi + 25690112);
    split_plane_k<<<12544, 256, 0, stream>>>(spatial, (long)B_*L_*D_, spA_hi, spA_lo);
    float* sppart = (float*)Wcat_hi;
    gemm_ws<<<dim3(4, 4, 49), 256, 0, stream>>>(
        spA_hi, spA_lo, D_, WvT_hi, WvT_lo, D_, sppart, B_*L_, KA_, 512);
    reduce_sp_k<<<3136, 256, 0, stream>>>((const float4*)sppart, (float4*)sp);

    // ---- gconst = global_ @ W_ih[:,512:]^T + b_ih + b_hh (Wglob staged in Wp) ----
    short* Wglob_hi = Wp_hi;                          // 33,554,432
    short* Wglob_lo = (short*)((char*)Wp_hi + 33554432);
    split_nt_k<<<dim3(2, H4_), 256, 0, stream>>>(W_ih + 512, ED_, H4_, D_, Wglob_hi, Wglob_lo, D_, 0);
    gemm_ws<<<dim3(64, 8, 1), 256, 0, stream>>>(
        g_hi, g_lo, D_, Wglob_hi, Wglob_lo, D_, arena, B_, H4_, 256);
    gred_k<<<(B_*H4_)/256, 256, 0, stream>>>(arena, b_ih, b_hh, gconst);

    // ---- loop weight planes ----
    split_nt_k<<<dim3(1, H4_), 256, 0, stream>>>(W_ih, ED_, H4_, E_, Wcat_hi, Wcat_lo, KT2_, 0);
    split_nt_k<<<dim3(2, H4_), 256, 0, stream>>>(W_hh, H_, H4_, H_, Wcat_hi, Wcat_lo, KT2_, E_);
    split_nt_k<<<dim3(2, VP_), 256, 0, stream>>>(W_p_w, H_, V_, H_, Wp_hi, Wp_lo, H_, 0);
    split_t_k<<<dim3(KA_/64, H_/64), 256, 0, stream>>>(W_g, H_, KA_, WgT_hi, WgT_lo);

    // ---- h0/m0 (planes + partials in arena) ----
    {
      short* WTh = (short*)arena;
      short* WTl = (short*)((char*)arena + 8388608);
      float* prt = (float*)((char*)arena + 16777216);   // 16 x 128 x 2048 f32
      split_t_k<<<dim3(H_/64, D_/64), 256, 0, stream>>>(W_init_h, D_, H_, WTh, WTl);
      gemm_ws<<<dim3(16, 16, 1), 256, 0, stream>>>(
          g_hi, g_lo, D_, WTh, WTl, D_, prt, B_, H_, 128);
      reduce_tanh_k<<<(B_*H_)/256, 256, 0, stream>>>(prt, 16, h, h_hi, h_lo);
      split_t_k<<<dim3(H_/64, D_/64), 256, 0, stream>>>(W_init_m, D_, H_, WTh, WTl);
      gemm_ws<<<dim3(16, 16, 1), 256, 0, stream>>>(
          g_hi, g_lo, D_, WTh, WTl, D_, prt, B_, H_, 128);
      reduce_tanh_k<<<(B_*H_)/256, 256, 0, stream>>>(prt, 16, m, nullptr, nullptr);
    }

    gather_xh2_k<<<B_, 256, 0, stream>>>(embed, h_hi, h_lo, tok, xh_hi, xh_lo);

    for (int t = 0; t < T_; ++t) {
      // gates: S=20, k_len=128 (K=2560)
      gemm_ws<<<dim3(64, 20, 1), 256, 0, stream>>>(
          xh_hi, xh_lo, KT2_, Wcat_hi, Wcat_lo, KT2_, arena, B_, H4_, 128);
      lstm_reduce_k<20><<<(B_*H_)/256, 256, 0, stream>>>(
          arena, gconst, nullptr, nullptr, h, m, h_hi, h_lo);
      // hg: S=32, k_len=64
      gemm_ws<<<dim3(4, 32, 1), 256, 0, stream>>>(
          h_hi, h_lo, H_, WgT_hi, WgT_lo, H_, arena, B_, KA_, 64);
      attn_k<32><<<dim3(B_, 2), 256, 0, stream>>>(sp, arena, w_h, spatial, h, a_hi, a_lo);
      // logits: S=16, k_len=128
      gemm_ws<<<dim3(79, 16, 1), 256, 0, stream>>>(
          a_hi, a_lo, H_, Wp_hi, Wp_lo, H_, arena, B_, VP_, 128);
      logits_argmax_k<16,true><<<B_, 256, 0, stream>>>(
          arena, W_p_b, out + (long)t * V_, tok, tokout + t,
          embed, h_hi, h_lo, xh_hi, xh_lo);
    }
  } else {
    // -------- fallback: fp32 weights, on-the-fly split (R4 path) --------
    float* sp    = (float*)(base + 0);
    float* WvTf  = (float*)(base + 12845056);
    float* WgTf  = (float*)(base + 17039360);
    float* h     = (float*)(base + 21233664);
    float* m     = (float*)(base + 22282240);
    short* h_hi  = (short*)(base + 24379392);
    short* h_lo  = (short*)(base + 24903680);
    short* a_hi  = (short*)(base + 25427968);
    short* a_lo  = (short*)(base + 25952256);
    short* xh_hi = (short*)(base + 26476544);
    short* xh_lo = (short*)(base + 27656192);
    int*   tok   = (int*)  (base + 28835840);
    float* arena = (float*)(base + 28836352);

    init_tok_k<<<1, 128, 0, stream>>>(tok);
    transpose_f32<<<dim3(KA_/64, D_/64), 256, 0, stream>>>(W_v, D_, KA_, WvTf);
    gemm_mfma<true><<<dim3(4, 1, 49), 256, 0, stream>>>(
        spatial, nullptr, D_, WvTf, D_, nullptr, 0, 1<<30, sp, B_*L_, KA_, KA_, D_);
    transpose_f32<<<dim3(KA_/64, H_/64), 256, 0, stream>>>(W_g, H_, KA_, WgTf);
    {
      float* WT  = arena;
      float* prt = (float*)((char*)arena + 16777216);
      transpose_f32<<<dim3(H_/64, D_/64), 256, 0, stream>>>(W_init_h, D_, H_, WT);
      gemm_mfma<true><<<dim3(16, 4, 1), 256, 0, stream>>>(
          global_, nullptr, D_, WT, D_, nullptr, 0, 1<<30, prt, B_, H_, H_, 512);
      reduce_tanh_k<<<(B_*H_)/256, 256, 0, stream>>>(prt, 4, h, h_hi, h_lo);
      transpose_f32<<<dim3(H_/64, D_/64), 256, 0, stream>>>(W_init_m, D_, H_, WT);
      gemm_mfma<true><<<dim3(16, 4, 1), 256, 0, stream>>>(
          global_, nullptr, D_, WT, D_, nullptr, 0, 1<<30, prt, B_, H_, H_, 512);
      reduce_tanh_k<<<(B_*H_)/256, 256, 0, stream>>>(prt, 4, m, nullptr, nullptr);
    }
    for (int t = 0; t < T_; ++t) {
      gather_xh_k<<<B_, 256, 0, stream>>>(embed, global_, h_hi, h_lo, tok, xh_hi, xh_lo);
      gemm_mfma<false><<<dim3(64, 8, 1), 256, 0, stream>>>(
          xh_hi, xh_lo, KT_, W_ih, ED_, W_hh, H_, ED_, arena, B_, H4_, H4_, 576);
      lstm_reduce_k<8><<<(B_*H_)/256, 256, 0, stream>>>(
          arena, nullptr, b_ih, b_hh, h, m, h_hi, h_lo);
      gemm_mfma<false><<<dim3(4, 16, 1), 256, 0, stream>>>(
          h_hi, h_lo, H_, WgTf, H_, nullptr, 0, 1<<30, arena, B_, KA_, KA_, 128);
      attn_k<16><<<dim3(B_, 2), 256, 0, stream>>>(sp, arena, w_h, spatial, h, a_hi, a_lo);
      gemm_mfma<false><<<dim3(79, 4, 1), 256, 0, stream>>>(
          a_hi, a_lo, H_, W_p_w, H_, nullptr, 0, 1<<30, arena, B_, VP_, V_, 512);
      logits_argmax_k<4,false><<<B_, 256, 0, stream>>>(
          arena, W_p_b, out + (long)t * V_, tok, tokout + t,
          nullptr, nullptr, nullptr, nullptr, nullptr);
    }
  }
}

// Round 7
// 3537.322 us; speedup vs baseline: 1.8026x; 1.5913x over previous
//
#include <hip/hip_runtime.h>
#include <math.h>

// Model_13348758356240 — R7: m97-style GEMM engine — global_load_lds(16B) staging
// of A and W into LDS (XOR-swizzled via pre-swizzled global source), 2 blocks/CU,
// vmcnt(0)+barrier per 64-k step. Everything else carried from R6.

typedef __attribute__((ext_vector_type(8))) short bf16x8;
typedef __attribute__((ext_vector_type(4))) float f32x4;

#define B_ 128
#define L_ 49
#define D_ 2048
#define H_ 2048
#define E_ 512
#define KA_ 512
#define V_ 10000
#define T_ 20
#define ED_ 2560
#define KT_ 4608
#define KT2_ 2560
#define H4_ 8192
#define VP_ 10112

__device__ __forceinline__ void split1(float x, short* hi, short* lo){
  unsigned u = __float_as_uint(x);
  *hi = (short)(u >> 16);
  float r = x - __uint_as_float(u & 0xffff0000u);
  *lo = (short)(__float_as_uint(r) >> 16);
}
__device__ __forceinline__ void split8(float4 a, float4 b, bf16x8& h, bf16x8& l){
  float xs[8] = {a.x,a.y,a.z,a.w,b.x,b.y,b.z,b.w};
#pragma unroll
  for (int i=0;i<8;++i){
    unsigned u = __float_as_uint(xs[i]);
    h[i] = (short)(u>>16);
    float r = xs[i] - __uint_as_float(u & 0xffff0000u);
    l[i] = (short)(__float_as_uint(r)>>16);
  }
}

#define MFMA16(d,a,b,c) d = __builtin_amdgcn_mfma_f32_16x16x32_bf16(a,b,c,0,0,0)

__device__ __forceinline__ void gl_lds16(const short* g, char* l){
  __builtin_amdgcn_global_load_lds(
      (const __attribute__((address_space(1))) unsigned int*)g,
      (__attribute__((address_space(3))) unsigned int*)l, 16, 0, 0);
}

// ============ R7 GEMM: Cp = A @ W^T (K-slice) via LDS staging ============
// A planes bf16 [Mtot][lda]; W planes bf16 [Np][ldw] (pad rows zeroed).
// Block: 256 thr = 4 waves; tile M=128, N=128, BK=64. Grid (nb, S, mb).
// LDS 64KB: W hi/lo @0/16K, A hi/lo @32K/48K; [row][slot^ (row&7)] 16B chunks.
// k_len % 64 == 0.
__global__ __launch_bounds__(256)
void gemm_lds(const short* __restrict__ Ah, const short* __restrict__ Al, int lda,
              const short* __restrict__ Wh, const short* __restrict__ Wl, int ldw,
              float* __restrict__ Cp, int Mtot, int Np, int k_len)
{
  __shared__ __align__(16) char smem[65536];
  const int tid = threadIdx.x;
  const int wid = tid >> 6, lane = tid & 63;
  const int lr = lane & 15, lg = lane >> 4;
  const int m0 = blockIdx.z * 128;
  const int nblk = blockIdx.x * 128;
  const int kb0 = blockIdx.y * k_len;

  // per-lane global-source swizzle for global_load_lds (rule #21):
  // lane i covers row (+i/8), k-chunk stored at slot i%8 <- logical chunk (i%8)^(i/8)
  const int li8 = lane >> 3;
  const int kx  = 8 * ((lane & 7) ^ li8);   // element offset within 64-k slice

  f32x4 acc[8][2];
#pragma unroll
  for (int i=0;i<8;++i)
#pragma unroll
    for (int r=0;r<4;++r){ acc[i][0][r]=0.f; acc[i][1][r]=0.f; }

  const int rA = wid*32 + lr, rB = rA + 16;
  const int sw7 = lr & 7;   // row&7 for all this lane's ds_reads

  for (int kt = 0; kt < k_len; kt += 64) {
    const int kb = kb0 + kt;
    // ---- stage: 16 x global_load_lds (1KB each) per wave ----
    if (wid == 0) {
#pragma unroll
      for (int j = 0; j < 16; ++j)
        gl_lds16(Wh + (long)(nblk + j*8 + li8)*ldw + kb + kx, smem + j*1024);
    } else if (wid == 1) {
#pragma unroll
      for (int j = 0; j < 16; ++j)
        gl_lds16(Wl + (long)(nblk + j*8 + li8)*ldw + kb + kx, smem + 16384 + j*1024);
    } else if (wid == 2) {
#pragma unroll
      for (int j = 0; j < 16; ++j)
        gl_lds16(Ah + (long)(m0 + j*8 + li8)*lda + kb + kx, smem + 32768 + j*1024);
    } else {
#pragma unroll
      for (int j = 0; j < 16; ++j)
        gl_lds16(Al + (long)(m0 + j*8 + li8)*lda + kb + kx, smem + 49152 + j*1024);
    }
    asm volatile("s_waitcnt vmcnt(0)");
    __syncthreads();

    // ---- compute 64-k: 2 halves x 48 MFMA ----
#pragma unroll
    for (int h = 0; h < 2; ++h) {
      const int c16 = (h<<2) + lg;
      const int swz = (c16 ^ sw7) << 4;
      const bf16x8 whA = *(const bf16x8*)(smem +         rA*128 + swz);
      const bf16x8 wlA = *(const bf16x8*)(smem + 16384 + rA*128 + swz);
      const bf16x8 whB = *(const bf16x8*)(smem +         rB*128 + swz);
      const bf16x8 wlB = *(const bf16x8*)(smem + 16384 + rB*128 + swz);
#pragma unroll
      for (int mt = 0; mt < 8; ++mt) {
        const int aoff = (mt*16 + lr)*128 + swz;
        const bf16x8 ah = *(const bf16x8*)(smem + 32768 + aoff);
        const bf16x8 al = *(const bf16x8*)(smem + 49152 + aoff);
        MFMA16(acc[mt][0], ah, whA, acc[mt][0]);
        MFMA16(acc[mt][1], ah, whB, acc[mt][1]);
        MFMA16(acc[mt][0], ah, wlA, acc[mt][0]);
        MFMA16(acc[mt][1], ah, wlB, acc[mt][1]);
        MFMA16(acc[mt][0], al, whA, acc[mt][0]);
        MFMA16(acc[mt][1], al, whB, acc[mt][1]);
      }
    }
    __syncthreads();
  }

  const long srow = (long)blockIdx.y * Mtot + m0;
#pragma unroll
  for (int mt=0; mt<8; ++mt)
#pragma unroll
    for (int nt=0; nt<2; ++nt){
      const int col = nblk + wid*32 + nt*16 + lr;
#pragma unroll
      for (int r=0; r<4; ++r)
        Cp[(srow + mt*16 + 4*lg + r)*Np + col] = acc[mt][nt][r];
    }
}

// ============ fallback GEMM: fp32 W, on-the-fly split ============
template<bool AF32>
__global__ __launch_bounds__(256)
void gemm_mfma(const void* Ahv, const void* Alv, int lda,
               const float* __restrict__ W1, int ldw1,
               const float* __restrict__ W2, int ldw2, int ksplit,
               float* __restrict__ Cp, int Mtot, int Np, int Nvalid, int k_len)
{
  const int tid = threadIdx.x;
  const int wid = tid >> 6, lane = tid & 63;
  const int lr = lane & 15, lg = lane >> 4;
  const int m0 = blockIdx.z * 128;
  const int nw = blockIdx.x * 128 + wid * 32;
  const int kb = blockIdx.y * k_len;

  int rowA = nw + lr;       if (rowA >= Nvalid) rowA = Nvalid - 1;
  int rowB = nw + 16 + lr;  if (rowB >= Nvalid) rowB = Nvalid - 1;

  f32x4 acc[8][2];
#pragma unroll
  for (int i=0;i<8;++i)
#pragma unroll
    for (int r=0;r<4;++r){ acc[i][0][r]=0.f; acc[i][1][r]=0.f; }

  for (int kk = 0; kk < k_len; kk += 32) {
    const int kg = kb + kk;
    const float *pA, *pB;
    if (W2 && kg >= ksplit) {
      pA = W2 + (long)rowA*ldw2 + (kg - ksplit) + 8*lg;
      pB = W2 + (long)rowB*ldw2 + (kg - ksplit) + 8*lg;
    } else {
      pA = W1 + (long)rowA*ldw1 + kg + 8*lg;
      pB = W1 + (long)rowB*ldw1 + kg + 8*lg;
    }
    bf16x8 whA, wlA, whB, wlB;
    split8(*(const float4*)pA, *(const float4*)(pA+4), whA, wlA);
    split8(*(const float4*)pB, *(const float4*)(pB+4), whB, wlB);

    bf16x8 ah[8], al[8];
    if constexpr (AF32) {
      const float* Af = (const float*)Ahv;
#pragma unroll
      for (int mt=0; mt<8; ++mt){
        const float* ap = Af + (long)(m0 + mt*16 + lr)*lda + kg + 8*lg;
        split8(*(const float4*)ap, *(const float4*)(ap+4), ah[mt], al[mt]);
      }
    } else {
      const short* Ah = (const short*)Ahv;
      const short* Al = (const short*)Alv;
#pragma unroll
      for (int mt=0; mt<8; ++mt){
        const long off = (long)(m0 + mt*16 + lr)*lda + kg + 8*lg;
        ah[mt] = *(const bf16x8*)(Ah + off);
        al[mt] = *(const bf16x8*)(Al + off);
      }
    }
#pragma unroll
    for (int mt=0; mt<8; ++mt){
      MFMA16(acc[mt][0], ah[mt], whA, acc[mt][0]);
      MFMA16(acc[mt][1], ah[mt], whB, acc[mt][1]);
      MFMA16(acc[mt][0], ah[mt], wlA, acc[mt][0]);
      MFMA16(acc[mt][1], ah[mt], wlB, acc[mt][1]);
      MFMA16(acc[mt][0], al[mt], whA, acc[mt][0]);
      MFMA16(acc[mt][1], al[mt], whB, acc[mt][1]);
    }
  }

  const long srow = (long)blockIdx.y * Mtot + m0;
#pragma unroll
  for (int mt=0; mt<8; ++mt)
#pragma unroll
    for (int nt=0; nt<2; ++nt){
      const int col = nw + nt*16 + lr;
#pragma unroll
      for (int r=0; r<4; ++r)
        Cp[(srow + mt*16 + 4*lg + r)*Np + col] = acc[mt][nt][r];
    }
}

// ============ prep kernels ============
__global__ __launch_bounds__(256)
void split_nt_k(const float* __restrict__ W, int src_ld, int Nv, int kcount,
                short* __restrict__ Wh, short* __restrict__ Wl, int ldo, int ko)
{
  const int n = blockIdx.y;
  const int k = blockIdx.x * 1024 + threadIdx.x * 4;
  if (k >= kcount) return;
  short4 hv, lv;
  if (n < Nv) {
    const float4 v = *(const float4*)&W[(long)n*src_ld + k];
    split1(v.x, &hv.x, &lv.x); split1(v.y, &hv.y, &lv.y);
    split1(v.z, &hv.z, &lv.z); split1(v.w, &hv.w, &lv.w);
  } else {
    hv.x=hv.y=hv.z=hv.w=0; lv.x=lv.y=lv.z=lv.w=0;
  }
  *(short4*)&Wh[(long)n*ldo + ko + k] = hv;
  *(short4*)&Wl[(long)n*ldo + ko + k] = lv;
}

__global__ __launch_bounds__(256)
void split_t_k(const float* __restrict__ in, int K, int N,
               short* __restrict__ Oh, short* __restrict__ Ol)
{
  __shared__ float t[64][65];
  const int tid = threadIdx.x;
  const int c0 = blockIdx.x * 64, r0 = blockIdx.y * 64;
  const int lx = tid & 63, ly = tid >> 6;
#pragma unroll
  for (int i = 0; i < 16; ++i)
    t[ly + 4*i][lx] = in[(long)(r0 + ly + 4*i) * N + c0 + lx];
  __syncthreads();
#pragma unroll
  for (int i = 0; i < 16; ++i) {
    short hh, ll;
    split1(t[lx][ly + 4*i], &hh, &ll);
    const long o = (long)(c0 + ly + 4*i) * K + r0 + lx;
    Oh[o] = hh; Ol[o] = ll;
  }
}

__global__ __launch_bounds__(256)
void split_plane_k(const float* __restrict__ in, long n,
                   short* __restrict__ oh, short* __restrict__ ol)
{
  const long i = ((long)blockIdx.x * 256 + threadIdx.x) * 4;
  if (i >= n) return;
  const float4 v = *(const float4*)&in[i];
  short4 hv, lv;
  split1(v.x, &hv.x, &lv.x); split1(v.y, &hv.y, &lv.y);
  split1(v.z, &hv.z, &lv.z); split1(v.w, &hv.w, &lv.w);
  *(short4*)&oh[i] = hv;
  *(short4*)&ol[i] = lv;
}

__global__ __launch_bounds__(256)
void transpose_f32(const float* __restrict__ in, int R, int C, float* __restrict__ out)
{
  __shared__ float t[64][65];
  const int tid = threadIdx.x;
  const int c0 = blockIdx.x * 64, r0 = blockIdx.y * 64;
  const int lx = tid & 63, ly = tid >> 6;
#pragma unroll
  for (int i = 0; i < 16; ++i)
    t[ly + 4*i][lx] = in[(long)(r0 + ly + 4*i) * C + c0 + lx];
  __syncthreads();
#pragma unroll
  for (int i = 0; i < 16; ++i)
    out[(long)(c0 + ly + 4*i) * R + r0 + lx] = t[lx][ly + 4*i];
}

__global__ void reduce_sp_k(const float4* __restrict__ p, float4* __restrict__ sp)
{
  const long i = (long)blockIdx.x * 256 + threadIdx.x;   // 802,816 float4s
  const long s = 802816;
  float4 a = p[i], b = p[i+s], c = p[i+2*s], d = p[i+3*s];
  float4 r;
  r.x = (a.x+b.x)+(c.x+d.x); r.y = (a.y+b.y)+(c.y+d.y);
  r.z = (a.z+b.z)+(c.z+d.z); r.w = (a.w+b.w)+(c.w+d.w);
  sp[i] = r;
}

__global__ __launch_bounds__(256)
void gred_k(const float* __restrict__ prt, const float* __restrict__ b_ih,
            const float* __restrict__ b_hh, float* __restrict__ gconst)
{
  const int idx = blockIdx.x * 256 + threadIdx.x;
  const int n = idx & (H4_ - 1);
  float s = b_ih[n] + b_hh[n];
#pragma unroll
  for (int sl = 0; sl < 8; ++sl) s += prt[(long)sl * (B_*H4_) + idx];
  gconst[idx] = s;
}

// ============ step kernels ============
__global__ void init_tok_k(int* tok) {
  if (threadIdx.x < B_) tok[threadIdx.x] = 1; // START_IDX
}

__global__ __launch_bounds__(256)
void reduce_tanh_k(const float* __restrict__ gp, int S, float* __restrict__ out,
                   short* __restrict__ ohi, short* __restrict__ olo)
{
  const int idx = blockIdx.x * 256 + threadIdx.x;
  float s = 0.f;
  for (int sl = 0; sl < S; ++sl) s += gp[(long)sl * (B_*H_) + idx];
  s = tanhf(s);
  out[idx] = s;
  if (ohi) split1(s, &ohi[idx], &olo[idx]);
}

__global__ void gather_xh2_k(const float* __restrict__ embed,
                             const short* __restrict__ h_hi, const short* __restrict__ h_lo,
                             const int* __restrict__ tok,
                             short* __restrict__ xh_hi, short* __restrict__ xh_lo)
{
  const int b = blockIdx.x, tid = threadIdx.x;
  const int tk = tok[b];
  short* rh = xh_hi + (long)b * KT2_;
  short* rl = xh_lo + (long)b * KT2_;
  const float* e = embed + (long)tk * E_;
  for (int i = tid; i < E_; i += 256) split1(e[i], &rh[i], &rl[i]);
  for (int i = tid; i < H_; i += 256) { rh[E_ + i] = h_hi[(long)b * H_ + i]; rl[E_ + i] = h_lo[(long)b * H_ + i]; }
}

__global__ void gather_xh_k(const float* __restrict__ embed, const float* __restrict__ global_,
                            const short* __restrict__ h_hi, const short* __restrict__ h_lo,
                            const int* __restrict__ tok,
                            short* __restrict__ xh_hi, short* __restrict__ xh_lo)
{
  const int b = blockIdx.x, tid = threadIdx.x;
  const int tk = tok[b];
  short* rh = xh_hi + (long)b * KT_;
  short* rl = xh_lo + (long)b * KT_;
  const float* e = embed + (long)tk * E_;
  for (int i = tid; i < E_; i += 256) split1(e[i], &rh[i], &rl[i]);
  for (int i = tid; i < D_; i += 256) split1(global_[(long)b * D_ + i], &rh[E_ + i], &rl[E_ + i]);
  for (int i = tid; i < H_; i += 256) { rh[ED_ + i] = h_hi[(long)b * H_ + i]; rl[ED_ + i] = h_lo[(long)b * H_ + i]; }
}

template<int S>
__global__ __launch_bounds__(256)
void lstm_reduce_k(const float* __restrict__ gp, const float* __restrict__ gconst,
                   const float* __restrict__ b1, const float* __restrict__ b2,
                   float* __restrict__ h, float* __restrict__ m,
                   short* __restrict__ h_hi, short* __restrict__ h_lo)
{
  const int idx = blockIdx.x * 256 + threadIdx.x;
  const int b = idx >> 11, n = idx & (H_ - 1);
  float g[4];
#pragma unroll
  for (int j = 0; j < 4; ++j) {
    float s = gconst ? gconst[(long)b * H4_ + j*H_ + n] : (b1[j*H_ + n] + b2[j*H_ + n]);
#pragma unroll
    for (int sl = 0; sl < S; ++sl) s += gp[((long)sl * B_ + b) * H4_ + j*H_ + n];
    g[j] = s;
  }
  const float si = 1.f / (1.f + expf(-g[0]));
  const float sf = 1.f / (1.f + expf(-g[1]));
  const float gg = tanhf(g[2]);
  const float so = 1.f / (1.f + expf(-g[3]));
  const float mn = sf * m[idx] + si * gg;
  const float hn = so * tanhf(mn);
  m[idx] = mn; h[idx] = hn;
  split1(hn, &h_hi[idx], &h_lo[idx]);
}

template<int SHG>
__global__ __launch_bounds__(256)
void attn_k(const float* __restrict__ sp_proj, const float* __restrict__ hgp,
            const float* __restrict__ w_h, const float* __restrict__ spatial,
            const float* __restrict__ h,
            short* __restrict__ a_hi, short* __restrict__ a_lo)
{
  const int b = blockIdx.x, half = blockIdx.y, tid = threadIdx.x;
  const int lane = tid & 63, wv = tid >> 6;
  __shared__ float hgs[KA_];
  __shared__ float whs[KA_];
  __shared__ float zs[L_];
  __shared__ float alph[L_];
  for (int i = tid; i < KA_; i += 256) {
    float s = 0.f;
#pragma unroll
    for (int sl = 0; sl < SHG; ++sl) s += hgp[((long)sl * B_ + b) * KA_ + i];
    hgs[i] = s; whs[i] = w_h[i];
  }
  __syncthreads();
  for (int l = wv; l < L_; l += 4) {
    const float* sp = sp_proj + ((long)b * L_ + l) * KA_;
    float s = 0.f;
    for (int k = lane; k < KA_; k += 64) s += whs[k] * tanhf(sp[k] + hgs[k]);
#pragma unroll
    for (int off = 32; off > 0; off >>= 1) s += __shfl_down(s, off);
    if (lane == 0) zs[l] = s;
  }
  __syncthreads();
  if (wv == 0) {
    float v = (lane < L_) ? zs[lane] : -INFINITY;
    float mx = v;
#pragma unroll
    for (int off = 32; off > 0; off >>= 1) mx = fmaxf(mx, __shfl_xor(mx, off));
    float e = (lane < L_) ? expf(v - mx) : 0.f;
    float sum = e;
#pragma unroll
    for (int off = 32; off > 0; off >>= 1) sum += __shfl_xor(sum, off);
    if (lane < L_) alph[lane] = e / sum;
  }
  __syncthreads();
  const int d4 = half * 256 + tid;
  const float4* h4 = (const float4*)h;
  const float4* sp4 = (const float4*)spatial;
  float4 acc = h4[(long)b * 512 + d4];
#pragma unroll 7
  for (int l = 0; l < L_; ++l) {
    const float w = alph[l];
    const float4 v = sp4[((long)b * L_ + l) * 512 + d4];
    acc.x = fmaf(w, v.x, acc.x); acc.y = fmaf(w, v.y, acc.y);
    acc.z = fmaf(w, v.z, acc.z); acc.w = fmaf(w, v.w, acc.w);
  }
  short4 hv, lv;
  split1(acc.x, &hv.x, &lv.x); split1(acc.y, &hv.y, &lv.y);
  split1(acc.z, &hv.z, &lv.z); split1(acc.w, &hv.w, &lv.w);
  *(short4*)&a_hi[(long)b * D_ + d4*4] = hv;
  *(short4*)&a_lo[(long)b * D_ + d4*4] = lv;
}

template<int S, bool GATHER>
__global__ __launch_bounds__(256)
void logits_argmax_k(const float* __restrict__ lp, const float* __restrict__ bias,
                     float* __restrict__ outL, int* __restrict__ tok,
                     float* __restrict__ tokout,
                     const float* __restrict__ embed,
                     const short* __restrict__ h_hi, const short* __restrict__ h_lo,
                     short* __restrict__ xh_hi, short* __restrict__ xh_lo)
{
  const int b = blockIdx.x, tid = threadIdx.x;
  float bv = -INFINITY; int bi = 0x7fffffff;
  for (int j = tid; j < V_; j += 256) {
    float v = bias[j];
#pragma unroll
    for (int sl = 0; sl < S; ++sl) v += lp[((long)sl * B_ + b) * VP_ + j];
    outL[(long)b * (T_*V_) + j] = v;
    if (v > bv) { bv = v; bi = j; }
  }
  __shared__ float sv[256];
  __shared__ int   si[256];
  sv[tid] = bv; si[tid] = bi;
  __syncthreads();
  for (int s = 128; s > 0; s >>= 1) {
    if (tid < s) {
      const float ov = sv[tid + s]; const int oi = si[tid + s];
      if (ov > sv[tid] || (ov == sv[tid] && oi < si[tid])) { sv[tid] = ov; si[tid] = oi; }
    }
    __syncthreads();
  }
  if (tid == 0) { tok[b] = si[0]; tokout[(long)b * T_] = (float)si[0]; }
  if (GATHER) {
    __syncthreads();
    const int tk = si[0];
    short* rh = xh_hi + (long)b * KT2_;
    short* rl = xh_lo + (long)b * KT2_;
    const float* e = embed + (long)tk * E_;
    for (int i = tid; i < E_; i += 256) split1(e[i], &rh[i], &rl[i]);
    for (int i = tid; i < H_; i += 256) { rh[E_+i] = h_hi[(long)b*H_ + i]; rl[E_+i] = h_lo[(long)b*H_ + i]; }
  }
}

// ============ host ============
extern "C" void kernel_launch(void* const* d_in, const int* in_sizes, int n_in,
                              void* d_out, int out_size, void* d_ws, size_t ws_size,
                              hipStream_t stream)
{
  const float* spatial  = (const float*)d_in[0];
  const float* global_  = (const float*)d_in[1];
  const float* embed    = (const float*)d_in[2];
  const float* W_ih     = (const float*)d_in[3];
  const float* W_hh     = (const float*)d_in[4];
  const float* b_ih     = (const float*)d_in[5];
  const float* b_hh     = (const float*)d_in[6];
  const float* W_v      = (const float*)d_in[7];
  const float* W_g      = (const float*)d_in[8];
  const float* w_h      = (const float*)d_in[9];
  const float* W_p_w    = (const float*)d_in[10];
  const float* W_p_b    = (const float*)d_in[11];
  const float* W_init_h = (const float*)d_in[12];
  const float* W_init_m = (const float*)d_in[13];
  float* out = (float*)d_out;
  float* tokout = out + (long)B_ * T_ * V_;

  char* base = (char*)d_ws;
  const size_t NEED_PRE = 282591744;
  const size_t NEED_FB  = 62390784;
  if (ws_size < NEED_FB) return;

  if (ws_size >= NEED_PRE) {
    float* sp      = (float*)(base + 0);           // 12,845,056
    float* h       = (float*)(base + 12845056);    //  1,048,576
    float* m       = (float*)(base + 13893632);    //  1,048,576
    short* h_hi    = (short*)(base + 14942208);    //    524,288
    short* h_lo    = (short*)(base + 15466496);
    short* a_hi    = (short*)(base + 15990784);
    short* a_lo    = (short*)(base + 16515072);
    short* xh_hi   = (short*)(base + 17039360);    //    655,360 (128 x 2560)
    short* xh_lo   = (short*)(base + 17694720);
    short* g_hi    = (short*)(base + 18350080);    //    524,288
    short* g_lo    = (short*)(base + 18874368);
    float* gconst  = (float*)(base + 19398656);    //  4,194,304
    int*   tok     = (int*)  (base + 23592960);    //        512
    float* arena   = (float*)(base + 23593472);    // 83,886,080
    short* Wcat_hi = (short*)(base + 107479552);   // 41,943,040 (8192 x 2560)
    short* Wcat_lo = (short*)(base + 149422592);
    short* Wp_hi   = (short*)(base + 191365632);   // 41,418,752 (10112 x 2048)
    short* Wp_lo   = (short*)(base + 232784384);
    short* WvT_hi  = (short*)(base + 274203136);   //  2,097,152
    short* WvT_lo  = (short*)(base + 276300288);
    short* WgT_hi  = (short*)(base + 278397440);
    short* WgT_lo  = (short*)(base + 280494592);

    init_tok_k<<<1, 128, 0, stream>>>(tok);
    split_plane_k<<<256, 256, 0, stream>>>(global_, (long)B_*D_, g_hi, g_lo);

    // ---- sp = spatial @ W_v (S=4, k_len=512) ----
    split_t_k<<<dim3(KA_/64, D_/64), 256, 0, stream>>>(W_v, D_, KA_, WvT_hi, WvT_lo);
    short* spA_hi = Wp_hi;
    short* spA_lo = (short*)((char*)Wp_hi + 25690112);
    split_plane_k<<<12544, 256, 0, stream>>>(spatial, (long)B_*L_*D_, spA_hi, spA_lo);
    float* sppart = (float*)Wcat_hi;
    gemm_lds<<<dim3(4, 4, 49), 256, 0, stream>>>(
        spA_hi, spA_lo, D_, WvT_hi, WvT_lo, D_, sppart, B_*L_, KA_, 512);
    reduce_sp_k<<<3136, 256, 0, stream>>>((const float4*)sppart, (float4*)sp);

    // ---- gconst = global_ @ W_ih[:,512:]^T + b_ih + b_hh ----
    short* Wglob_hi = Wp_hi;
    short* Wglob_lo = (short*)((char*)Wp_hi + 33554432);
    split_nt_k<<<dim3(2, H4_), 256, 0, stream>>>(W_ih + 512, ED_, H4_, D_, Wglob_hi, Wglob_lo, D_, 0);
    gemm_lds<<<dim3(64, 8, 1), 256, 0, stream>>>(
        g_hi, g_lo, D_, Wglob_hi, Wglob_lo, D_, arena, B_, H4_, 256);
    gred_k<<<(B_*H4_)/256, 256, 0, stream>>>(arena, b_ih, b_hh, gconst);

    // ---- loop weight planes ----
    split_nt_k<<<dim3(1, H4_), 256, 0, stream>>>(W_ih, ED_, H4_, E_, Wcat_hi, Wcat_lo, KT2_, 0);
    split_nt_k<<<dim3(2, H4_), 256, 0, stream>>>(W_hh, H_, H4_, H_, Wcat_hi, Wcat_lo, KT2_, E_);
    split_nt_k<<<dim3(2, VP_), 256, 0, stream>>>(W_p_w, H_, V_, H_, Wp_hi, Wp_lo, H_, 0);
    split_t_k<<<dim3(KA_/64, H_/64), 256, 0, stream>>>(W_g, H_, KA_, WgT_hi, WgT_lo);

    // ---- h0/m0 (S=16, k_len=128) ----
    {
      short* WTh = (short*)arena;
      short* WTl = (short*)((char*)arena + 8388608);
      float* prt = (float*)((char*)arena + 16777216);
      split_t_k<<<dim3(H_/64, D_/64), 256, 0, stream>>>(W_init_h, D_, H_, WTh, WTl);
      gemm_lds<<<dim3(16, 16, 1), 256, 0, stream>>>(
          g_hi, g_lo, D_, WTh, WTl, D_, prt, B_, H_, 128);
      reduce_tanh_k<<<(B_*H_)/256, 256, 0, stream>>>(prt, 16, h, h_hi, h_lo);
      split_t_k<<<dim3(H_/64, D_/64), 256, 0, stream>>>(W_init_m, D_, H_, WTh, WTl);
      gemm_lds<<<dim3(16, 16, 1), 256, 0, stream>>>(
          g_hi, g_lo, D_, WTh, WTl, D_, prt, B_, H_, 128);
      reduce_tanh_k<<<(B_*H_)/256, 256, 0, stream>>>(prt, 16, m, nullptr, nullptr);
    }

    gather_xh2_k<<<B_, 256, 0, stream>>>(embed, h_hi, h_lo, tok, xh_hi, xh_lo);

    for (int t = 0; t < T_; ++t) {
      // gates: S=8, k_len=320 (K=2560) -> 512 blocks = 2/CU
      gemm_lds<<<dim3(64, 8, 1), 256, 0, stream>>>(
          xh_hi, xh_lo, KT2_, Wcat_hi, Wcat_lo, KT2_, arena, B_, H4_, 320);
      lstm_reduce_k<8><<<(B_*H_)/256, 256, 0, stream>>>(
          arena, gconst, nullptr, nullptr, h, m, h_hi, h_lo);
      // hg: S=32, k_len=64 -> 128 blocks
      gemm_lds<<<dim3(4, 32, 1), 256, 0, stream>>>(
          h_hi, h_lo, H_, WgT_hi, WgT_lo, H_, arena, B_, KA_, 64);
      attn_k<32><<<dim3(B_, 2), 256, 0, stream>>>(sp, arena, w_h, spatial, h, a_hi, a_lo);
      // logits: S=8, k_len=256 -> 632 blocks
      gemm_lds<<<dim3(79, 8, 1), 256, 0, stream>>>(
          a_hi, a_lo, H_, Wp_hi, Wp_lo, H_, arena, B_, VP_, 256);
      logits_argmax_k<8,true><<<B_, 256, 0, stream>>>(
          arena, W_p_b, out + (long)t * V_, tok, tokout + t,
          embed, h_hi, h_lo, xh_hi, xh_lo);
    }
  } else {
    // -------- fallback: fp32 weights, on-the-fly split --------
    float* sp    = (float*)(base + 0);
    float* WvTf  = (float*)(base + 12845056);
    float* WgTf  = (float*)(base + 17039360);
    float* h     = (float*)(base + 21233664);
    float* m     = (float*)(base + 22282240);
    short* h_hi  = (short*)(base + 24379392);
    short* h_lo  = (short*)(base + 24903680);
    short* a_hi  = (short*)(base + 25427968);
    short* a_lo  = (short*)(base + 25952256);
    short* xh_hi = (short*)(base + 26476544);
    short* xh_lo = (short*)(base + 27656192);
    int*   tok   = (int*)  (base + 28835840);
    float* arena = (float*)(base + 28836352);

    init_tok_k<<<1, 128, 0, stream>>>(tok);
    transpose_f32<<<dim3(KA_/64, D_/64), 256, 0, stream>>>(W_v, D_, KA_, WvTf);
    gemm_mfma<true><<<dim3(4, 1, 49), 256, 0, stream>>>(
        spatial, nullptr, D_, WvTf, D_, nullptr, 0, 1<<30, sp, B_*L_, KA_, KA_, D_);
    transpose_f32<<<dim3(KA_/64, H_/64), 256, 0, stream>>>(W_g, H_, KA_, WgTf);
    {
      float* WT  = arena;
      float* prt = (float*)((char*)arena + 16777216);
      transpose_f32<<<dim3(H_/64, D_/64), 256, 0, stream>>>(W_init_h, D_, H_, WT);
      gemm_mfma<true><<<dim3(16, 4, 1), 256, 0, stream>>>(
          global_, nullptr, D_, WT, D_, nullptr, 0, 1<<30, prt, B_, H_, H_, 512);
      reduce_tanh_k<<<(B_*H_)/256, 256, 0, stream>>>(prt, 4, h, h_hi, h_lo);
      transpose_f32<<<dim3(H_/64, D_/64), 256, 0, stream>>>(W_init_m, D_, H_, WT);
      gemm_mfma<true><<<dim3(16, 4, 1), 256, 0, stream>>>(
          global_, nullptr, D_, WT, D_, nullptr, 0, 1<<30, prt, B_, H_, H_, 512);
      reduce_tanh_k<<<(B_*H_)/256, 256, 0, stream>>>(prt, 4, m, nullptr, nullptr);
    }
    for (int t = 0; t < T_; ++t) {
      gather_xh_k<<<B_, 256, 0, stream>>>(embed, global_, h_hi, h_lo, tok, xh_hi, xh_lo);
      gemm_mfma<false><<<dim3(64, 8, 1), 256, 0, stream>>>(
          xh_hi, xh_lo, KT_, W_ih, ED_, W_hh, H_, ED_, arena, B_, H4_, H4_, 576);
      lstm_reduce_k<8><<<(B_*H_)/256, 256, 0, stream>>>(
          arena, nullptr, b_ih, b_hh, h, m, h_hi, h_lo);
      gemm_mfma<false><<<dim3(4, 16, 1), 256, 0, stream>>>(
          h_hi, h_lo, H_, WgTf, H_, nullptr, 0, 1<<30, arena, B_, KA_, KA_, 128);
      attn_k<16><<<dim3(B_, 2), 256, 0, stream>>>(sp, arena, w_h, spatial, h, a_hi, a_lo);
      gemm_mfma<false><<<dim3(79, 4, 1), 256, 0, stream>>>(
          a_hi, a_lo, H_, W_p_w, H_, nullptr, 0, 1<<30, arena, B_, VP_, V_, 512);
      logits_argmax_k<4,false><<<B_, 256, 0, stream>>>(
          arena, W_p_b, out + (long)t * V_, tok, tokout + t,
          nullptr, nullptr, nullptr, nullptr, nullptr);
    }
  }
}

// Round 8
// 2705.149 us; speedup vs baseline: 2.3571x; 1.3076x over previous
//
#include <hip/hip_runtime.h>
#include <math.h>

// Model_13348758356240 — R8: attn split into hgred/z/c/comb parallel kernels
// (kills the 72µs latency-bound attn_k). GEMM engine = R7 global_load_lds LDS
// staging with XOR swizzle. gconst algebra + split-K grids carried from R6/R7.

typedef __attribute__((ext_vector_type(8))) short bf16x8;
typedef __attribute__((ext_vector_type(4))) float f32x4;

#define B_ 128
#define L_ 49
#define D_ 2048
#define H_ 2048
#define E_ 512
#define KA_ 512
#define V_ 10000
#define T_ 20
#define ED_ 2560
#define KT_ 4608
#define KT2_ 2560
#define H4_ 8192
#define VP_ 10112

__device__ __forceinline__ void split1(float x, short* hi, short* lo){
  unsigned u = __float_as_uint(x);
  *hi = (short)(u >> 16);
  float r = x - __uint_as_float(u & 0xffff0000u);
  *lo = (short)(__float_as_uint(r) >> 16);
}
__device__ __forceinline__ void split8(float4 a, float4 b, bf16x8& h, bf16x8& l){
  float xs[8] = {a.x,a.y,a.z,a.w,b.x,b.y,b.z,b.w};
#pragma unroll
  for (int i=0;i<8;++i){
    unsigned u = __float_as_uint(xs[i]);
    h[i] = (short)(u>>16);
    float r = xs[i] - __uint_as_float(u & 0xffff0000u);
    l[i] = (short)(__float_as_uint(r)>>16);
  }
}

#define MFMA16(d,a,b,c) d = __builtin_amdgcn_mfma_f32_16x16x32_bf16(a,b,c,0,0,0)

__device__ __forceinline__ void gl_lds16(const short* g, char* l){
  __builtin_amdgcn_global_load_lds(
      (const __attribute__((address_space(1))) unsigned int*)g,
      (__attribute__((address_space(3))) unsigned int*)l, 16, 0, 0);
}

// ============ GEMM: Cp = A @ W^T (K-slice) via LDS staging (R7) ============
__global__ __launch_bounds__(256)
void gemm_lds(const short* __restrict__ Ah, const short* __restrict__ Al, int lda,
              const short* __restrict__ Wh, const short* __restrict__ Wl, int ldw,
              float* __restrict__ Cp, int Mtot, int Np, int k_len)
{
  __shared__ __align__(16) char smem[65536];
  const int tid = threadIdx.x;
  const int wid = tid >> 6, lane = tid & 63;
  const int lr = lane & 15, lg = lane >> 4;
  const int m0 = blockIdx.z * 128;
  const int nblk = blockIdx.x * 128;
  const int kb0 = blockIdx.y * k_len;

  const int li8 = lane >> 3;
  const int kx  = 8 * ((lane & 7) ^ li8);

  f32x4 acc[8][2];
#pragma unroll
  for (int i=0;i<8;++i)
#pragma unroll
    for (int r=0;r<4;++r){ acc[i][0][r]=0.f; acc[i][1][r]=0.f; }

  const int rA = wid*32 + lr, rB = rA + 16;
  const int sw7 = lr & 7;

  for (int kt = 0; kt < k_len; kt += 64) {
    const int kb = kb0 + kt;
    if (wid == 0) {
#pragma unroll
      for (int j = 0; j < 16; ++j)
        gl_lds16(Wh + (long)(nblk + j*8 + li8)*ldw + kb + kx, smem + j*1024);
    } else if (wid == 1) {
#pragma unroll
      for (int j = 0; j < 16; ++j)
        gl_lds16(Wl + (long)(nblk + j*8 + li8)*ldw + kb + kx, smem + 16384 + j*1024);
    } else if (wid == 2) {
#pragma unroll
      for (int j = 0; j < 16; ++j)
        gl_lds16(Ah + (long)(m0 + j*8 + li8)*lda + kb + kx, smem + 32768 + j*1024);
    } else {
#pragma unroll
      for (int j = 0; j < 16; ++j)
        gl_lds16(Al + (long)(m0 + j*8 + li8)*lda + kb + kx, smem + 49152 + j*1024);
    }
    asm volatile("s_waitcnt vmcnt(0)");
    __syncthreads();

#pragma unroll
    for (int h = 0; h < 2; ++h) {
      const int c16 = (h<<2) + lg;
      const int swz = (c16 ^ sw7) << 4;
      const bf16x8 whA = *(const bf16x8*)(smem +         rA*128 + swz);
      const bf16x8 wlA = *(const bf16x8*)(smem + 16384 + rA*128 + swz);
      const bf16x8 whB = *(const bf16x8*)(smem +         rB*128 + swz);
      const bf16x8 wlB = *(const bf16x8*)(smem + 16384 + rB*128 + swz);
#pragma unroll
      for (int mt = 0; mt < 8; ++mt) {
        const int aoff = (mt*16 + lr)*128 + swz;
        const bf16x8 ah = *(const bf16x8*)(smem + 32768 + aoff);
        const bf16x8 al = *(const bf16x8*)(smem + 49152 + aoff);
        MFMA16(acc[mt][0], ah, whA, acc[mt][0]);
        MFMA16(acc[mt][1], ah, whB, acc[mt][1]);
        MFMA16(acc[mt][0], ah, wlA, acc[mt][0]);
        MFMA16(acc[mt][1], ah, wlB, acc[mt][1]);
        MFMA16(acc[mt][0], al, whA, acc[mt][0]);
        MFMA16(acc[mt][1], al, whB, acc[mt][1]);
      }
    }
    __syncthreads();
  }

  const long srow = (long)blockIdx.y * Mtot + m0;
#pragma unroll
  for (int mt=0; mt<8; ++mt)
#pragma unroll
    for (int nt=0; nt<2; ++nt){
      const int col = nblk + wid*32 + nt*16 + lr;
#pragma unroll
      for (int r=0; r<4; ++r)
        Cp[(srow + mt*16 + 4*lg + r)*Np + col] = acc[mt][nt][r];
    }
}

// ============ fallback GEMM: fp32 W, on-the-fly split ============
template<bool AF32>
__global__ __launch_bounds__(256)
void gemm_mfma(const void* Ahv, const void* Alv, int lda,
               const float* __restrict__ W1, int ldw1,
               const float* __restrict__ W2, int ldw2, int ksplit,
               float* __restrict__ Cp, int Mtot, int Np, int Nvalid, int k_len)
{
  const int tid = threadIdx.x;
  const int wid = tid >> 6, lane = tid & 63;
  const int lr = lane & 15, lg = lane >> 4;
  const int m0 = blockIdx.z * 128;
  const int nw = blockIdx.x * 128 + wid * 32;
  const int kb = blockIdx.y * k_len;

  int rowA = nw + lr;       if (rowA >= Nvalid) rowA = Nvalid - 1;
  int rowB = nw + 16 + lr;  if (rowB >= Nvalid) rowB = Nvalid - 1;

  f32x4 acc[8][2];
#pragma unroll
  for (int i=0;i<8;++i)
#pragma unroll
    for (int r=0;r<4;++r){ acc[i][0][r]=0.f; acc[i][1][r]=0.f; }

  for (int kk = 0; kk < k_len; kk += 32) {
    const int kg = kb + kk;
    const float *pA, *pB;
    if (W2 && kg >= ksplit) {
      pA = W2 + (long)rowA*ldw2 + (kg - ksplit) + 8*lg;
      pB = W2 + (long)rowB*ldw2 + (kg - ksplit) + 8*lg;
    } else {
      pA = W1 + (long)rowA*ldw1 + kg + 8*lg;
      pB = W1 + (long)rowB*ldw1 + kg + 8*lg;
    }
    bf16x8 whA, wlA, whB, wlB;
    split8(*(const float4*)pA, *(const float4*)(pA+4), whA, wlA);
    split8(*(const float4*)pB, *(const float4*)(pB+4), whB, wlB);

    bf16x8 ah[8], al[8];
    if constexpr (AF32) {
      const float* Af = (const float*)Ahv;
#pragma unroll
      for (int mt=0; mt<8; ++mt){
        const float* ap = Af + (long)(m0 + mt*16 + lr)*lda + kg + 8*lg;
        split8(*(const float4*)ap, *(const float4*)(ap+4), ah[mt], al[mt]);
      }
    } else {
      const short* Ah = (const short*)Ahv;
      const short* Al = (const short*)Alv;
#pragma unroll
      for (int mt=0; mt<8; ++mt){
        const long off = (long)(m0 + mt*16 + lr)*lda + kg + 8*lg;
        ah[mt] = *(const bf16x8*)(Ah + off);
        al[mt] = *(const bf16x8*)(Al + off);
      }
    }
#pragma unroll
    for (int mt=0; mt<8; ++mt){
      MFMA16(acc[mt][0], ah[mt], whA, acc[mt][0]);
      MFMA16(acc[mt][1], ah[mt], whB, acc[mt][1]);
      MFMA16(acc[mt][0], ah[mt], wlA, acc[mt][0]);
      MFMA16(acc[mt][1], ah[mt], wlB, acc[mt][1]);
      MFMA16(acc[mt][0], al[mt], whA, acc[mt][0]);
      MFMA16(acc[mt][1], al[mt], whB, acc[mt][1]);
    }
  }

  const long srow = (long)blockIdx.y * Mtot + m0;
#pragma unroll
  for (int mt=0; mt<8; ++mt)
#pragma unroll
    for (int nt=0; nt<2; ++nt){
      const int col = nw + nt*16 + lr;
#pragma unroll
      for (int r=0; r<4; ++r)
        Cp[(srow + mt*16 + 4*lg + r)*Np + col] = acc[mt][nt][r];
    }
}

// ============ prep kernels ============
__global__ __launch_bounds__(256)
void split_nt_k(const float* __restrict__ W, int src_ld, int Nv, int kcount,
                short* __restrict__ Wh, short* __restrict__ Wl, int ldo, int ko)
{
  const int n = blockIdx.y;
  const int k = blockIdx.x * 1024 + threadIdx.x * 4;
  if (k >= kcount) return;
  short4 hv, lv;
  if (n < Nv) {
    const float4 v = *(const float4*)&W[(long)n*src_ld + k];
    split1(v.x, &hv.x, &lv.x); split1(v.y, &hv.y, &lv.y);
    split1(v.z, &hv.z, &lv.z); split1(v.w, &hv.w, &lv.w);
  } else {
    hv.x=hv.y=hv.z=hv.w=0; lv.x=lv.y=lv.z=lv.w=0;
  }
  *(short4*)&Wh[(long)n*ldo + ko + k] = hv;
  *(short4*)&Wl[(long)n*ldo + ko + k] = lv;
}

__global__ __launch_bounds__(256)
void split_t_k(const float* __restrict__ in, int K, int N,
               short* __restrict__ Oh, short* __restrict__ Ol)
{
  __shared__ float t[64][65];
  const int tid = threadIdx.x;
  const int c0 = blockIdx.x * 64, r0 = blockIdx.y * 64;
  const int lx = tid & 63, ly = tid >> 6;
#pragma unroll
  for (int i = 0; i < 16; ++i)
    t[ly + 4*i][lx] = in[(long)(r0 + ly + 4*i) * N + c0 + lx];
  __syncthreads();
#pragma unroll
  for (int i = 0; i < 16; ++i) {
    short hh, ll;
    split1(t[lx][ly + 4*i], &hh, &ll);
    const long o = (long)(c0 + ly + 4*i) * K + r0 + lx;
    Oh[o] = hh; Ol[o] = ll;
  }
}

__global__ __launch_bounds__(256)
void split_plane_k(const float* __restrict__ in, long n,
                   short* __restrict__ oh, short* __restrict__ ol)
{
  const long i = ((long)blockIdx.x * 256 + threadIdx.x) * 4;
  if (i >= n) return;
  const float4 v = *(const float4*)&in[i];
  short4 hv, lv;
  split1(v.x, &hv.x, &lv.x); split1(v.y, &hv.y, &lv.y);
  split1(v.z, &hv.z, &lv.z); split1(v.w, &hv.w, &lv.w);
  *(short4*)&oh[i] = hv;
  *(short4*)&ol[i] = lv;
}

__global__ __launch_bounds__(256)
void transpose_f32(const float* __restrict__ in, int R, int C, float* __restrict__ out)
{
  __shared__ float t[64][65];
  const int tid = threadIdx.x;
  const int c0 = blockIdx.x * 64, r0 = blockIdx.y * 64;
  const int lx = tid & 63, ly = tid >> 6;
#pragma unroll
  for (int i = 0; i < 16; ++i)
    t[ly + 4*i][lx] = in[(long)(r0 + ly + 4*i) * C + c0 + lx];
  __syncthreads();
#pragma unroll
  for (int i = 0; i < 16; ++i)
    out[(long)(c0 + ly + 4*i) * R + r0 + lx] = t[lx][ly + 4*i];
}

__global__ void reduce_sp_k(const float4* __restrict__ p, float4* __restrict__ sp)
{
  const long i = (long)blockIdx.x * 256 + threadIdx.x;
  const long s = 802816;
  float4 a = p[i], b = p[i+s], c = p[i+2*s], d = p[i+3*s];
  float4 r;
  r.x = (a.x+b.x)+(c.x+d.x); r.y = (a.y+b.y)+(c.y+d.y);
  r.z = (a.z+b.z)+(c.z+d.z); r.w = (a.w+b.w)+(c.w+d.w);
  sp[i] = r;
}

__global__ __launch_bounds__(256)
void gred_k(const float* __restrict__ prt, const float* __restrict__ b_ih,
            const float* __restrict__ b_hh, float* __restrict__ gconst)
{
  const int idx = blockIdx.x * 256 + threadIdx.x;
  const int n = idx & (H4_ - 1);
  float s = b_ih[n] + b_hh[n];
#pragma unroll
  for (int sl = 0; sl < 8; ++sl) s += prt[(long)sl * (B_*H4_) + idx];
  gconst[idx] = s;
}

// ============ step kernels ============
__global__ void init_tok_k(int* tok) {
  if (threadIdx.x < B_) tok[threadIdx.x] = 1; // START_IDX
}

__global__ __launch_bounds__(256)
void reduce_tanh_k(const float* __restrict__ gp, int S, float* __restrict__ out,
                   short* __restrict__ ohi, short* __restrict__ olo)
{
  const int idx = blockIdx.x * 256 + threadIdx.x;
  float s = 0.f;
  for (int sl = 0; sl < S; ++sl) s += gp[(long)sl * (B_*H_) + idx];
  s = tanhf(s);
  out[idx] = s;
  if (ohi) split1(s, &ohi[idx], &olo[idx]);
}

__global__ void gather_xh2_k(const float* __restrict__ embed,
                             const short* __restrict__ h_hi, const short* __restrict__ h_lo,
                             const int* __restrict__ tok,
                             short* __restrict__ xh_hi, short* __restrict__ xh_lo)
{
  const int b = blockIdx.x, tid = threadIdx.x;
  const int tk = tok[b];
  short* rh = xh_hi + (long)b * KT2_;
  short* rl = xh_lo + (long)b * KT2_;
  const float* e = embed + (long)tk * E_;
  for (int i = tid; i < E_; i += 256) split1(e[i], &rh[i], &rl[i]);
  for (int i = tid; i < H_; i += 256) { rh[E_ + i] = h_hi[(long)b * H_ + i]; rl[E_ + i] = h_lo[(long)b * H_ + i]; }
}

__global__ void gather_xh_k(const float* __restrict__ embed, const float* __restrict__ global_,
                            const short* __restrict__ h_hi, const short* __restrict__ h_lo,
                            const int* __restrict__ tok,
                            short* __restrict__ xh_hi, short* __restrict__ xh_lo)
{
  const int b = blockIdx.x, tid = threadIdx.x;
  const int tk = tok[b];
  short* rh = xh_hi + (long)b * KT_;
  short* rl = xh_lo + (long)b * KT_;
  const float* e = embed + (long)tk * E_;
  for (int i = tid; i < E_; i += 256) split1(e[i], &rh[i], &rl[i]);
  for (int i = tid; i < D_; i += 256) split1(global_[(long)b * D_ + i], &rh[E_ + i], &rl[E_ + i]);
  for (int i = tid; i < H_; i += 256) { rh[ED_ + i] = h_hi[(long)b * H_ + i]; rl[ED_ + i] = h_lo[(long)b * H_ + i]; }
}

template<int S>
__global__ __launch_bounds__(256)
void lstm_reduce_k(const float* __restrict__ gp, const float* __restrict__ gconst,
                   const float* __restrict__ b1, const float* __restrict__ b2,
                   float* __restrict__ h, float* __restrict__ m,
                   short* __restrict__ h_hi, short* __restrict__ h_lo)
{
  const int idx = blockIdx.x * 256 + threadIdx.x;
  const int b = idx >> 11, n = idx & (H_ - 1);
  float g[4];
#pragma unroll
  for (int j = 0; j < 4; ++j) {
    float s = gconst ? gconst[(long)b * H4_ + j*H_ + n] : (b1[j*H_ + n] + b2[j*H_ + n]);
#pragma unroll
    for (int sl = 0; sl < S; ++sl) s += gp[((long)sl * B_ + b) * H4_ + j*H_ + n];
    g[j] = s;
  }
  const float si = 1.f / (1.f + expf(-g[0]));
  const float sf = 1.f / (1.f + expf(-g[1]));
  const float gg = tanhf(g[2]);
  const float so = 1.f / (1.f + expf(-g[3]));
  const float mn = sf * m[idx] + si * gg;
  const float hn = so * tanhf(mn);
  m[idx] = mn; h[idx] = hn;
  split1(hn, &h_hi[idx], &h_lo[idx]);
}

// ---- R8 attention pipeline ----
// hg = sum_32 hgp  (independent loads)
__global__ __launch_bounds__(256)
void hgred_k(const float* __restrict__ hgp, float* __restrict__ hg)
{
  const int idx = blockIdx.x * 256 + threadIdx.x;   // 0..B*KA-1
  float s = 0.f;
#pragma unroll
  for (int sl = 0; sl < 32; ++sl) s += hgp[(long)sl * (B_*KA_) + idx];
  hg[idx] = s;
}

// z[b*49+l] = w_h . tanh(sp[b,l,:] + hg[b,:]) — one wave per (b,l)
__global__ __launch_bounds__(256)
void z_k(const float* __restrict__ sp, const float* __restrict__ hg,
         const float* __restrict__ w_h, float* __restrict__ z)
{
  const int wid = threadIdx.x >> 6, lane = threadIdx.x & 63;
  const int p = blockIdx.x * 4 + wid;           // 0..6271
  const int b = p / L_, l = p - b * L_;
  const float4* spv = (const float4*)(sp + ((long)b * L_ + l) * KA_);
  const float4* hgv = (const float4*)(hg + (long)b * KA_);
  const float4* whv = (const float4*)w_h;
  const int k4 = lane * 2;
  const float4 s1 = spv[k4], s2 = spv[k4+1];
  const float4 h1 = hgv[k4], h2 = hgv[k4+1];
  const float4 w1 = whv[k4], w2 = whv[k4+1];
  float s = w1.x * tanhf(s1.x + h1.x) + w1.y * tanhf(s1.y + h1.y)
          + w1.z * tanhf(s1.z + h1.z) + w1.w * tanhf(s1.w + h1.w)
          + w2.x * tanhf(s2.x + h2.x) + w2.y * tanhf(s2.y + h2.y)
          + w2.z * tanhf(s2.z + h2.z) + w2.w * tanhf(s2.w + h2.w);
#pragma unroll
  for (int off = 32; off > 0; off >>= 1) s += __shfl_down(s, off);
  if (lane == 0) z[p] = s;
}

// cpart[lh][b][:] — softmax(z) recomputed per block (cheap), partial alpha@spatial
__global__ __launch_bounds__(256)
void c_k(const float* __restrict__ z, const float* __restrict__ spatial,
         float* __restrict__ cpart)
{
  const int b = blockIdx.x, y = blockIdx.y;
  const int dh = y & 1, lh = y >> 1;
  const int tid = threadIdx.x, lane = tid & 63;
  __shared__ float alph[L_];
  if (tid < 64) {
    float v = (lane < L_) ? z[b * L_ + lane] : -INFINITY;
    float mx = v;
#pragma unroll
    for (int off = 32; off > 0; off >>= 1) mx = fmaxf(mx, __shfl_xor(mx, off));
    float e = (lane < L_) ? expf(v - mx) : 0.f;
    float sum = e;
#pragma unroll
    for (int off = 32; off > 0; off >>= 1) sum += __shfl_xor(sum, off);
    if (lane < L_) alph[lane] = e / sum;
  }
  __syncthreads();
  const int l0 = lh ? 25 : 0, l1 = lh ? L_ : 25;
  const int d4 = dh * 256 + tid;
  const float4* sp4 = (const float4*)spatial;
  float4 acc; acc.x = 0.f; acc.y = 0.f; acc.z = 0.f; acc.w = 0.f;
#pragma unroll 5
  for (int l = l0; l < l1; ++l) {
    const float w = alph[l];
    const float4 v = sp4[((long)b * L_ + l) * 512 + d4];
    acc.x = fmaf(w, v.x, acc.x); acc.y = fmaf(w, v.y, acc.y);
    acc.z = fmaf(w, v.z, acc.z); acc.w = fmaf(w, v.w, acc.w);
  }
  ((float4*)cpart)[((long)lh * B_ + b) * 512 + d4] = acc;
}

// a = h + cpart0 + cpart1 -> bf16 planes
__global__ __launch_bounds__(256)
void comb_k(const float* __restrict__ cpart, const float* __restrict__ h,
            short* __restrict__ a_hi, short* __restrict__ a_lo)
{
  const int i4 = blockIdx.x * 256 + threadIdx.x;   // 0..65535 float4s
  const float4 hv4 = ((const float4*)h)[i4];
  const float4 p0 = ((const float4*)cpart)[i4];
  const float4 p1 = ((const float4*)cpart)[65536 + i4];
  float4 a;
  a.x = hv4.x + p0.x + p1.x; a.y = hv4.y + p0.y + p1.y;
  a.z = hv4.z + p0.z + p1.z; a.w = hv4.w + p0.w + p1.w;
  short4 hv, lv;
  split1(a.x, &hv.x, &lv.x); split1(a.y, &hv.y, &lv.y);
  split1(a.z, &hv.z, &lv.z); split1(a.w, &hv.w, &lv.w);
  *(short4*)&a_hi[i4*4] = hv;
  *(short4*)&a_lo[i4*4] = lv;
}

// fallback monolithic attn (R6)
template<int SHG>
__global__ __launch_bounds__(256)
void attn_k(const float* __restrict__ sp_proj, const float* __restrict__ hgp,
            const float* __restrict__ w_h, const float* __restrict__ spatial,
            const float* __restrict__ h,
            short* __restrict__ a_hi, short* __restrict__ a_lo)
{
  const int b = blockIdx.x, half = blockIdx.y, tid = threadIdx.x;
  const int lane = tid & 63, wv = tid >> 6;
  __shared__ float hgs[KA_];
  __shared__ float whs[KA_];
  __shared__ float zs[L_];
  __shared__ float alph[L_];
  for (int i = tid; i < KA_; i += 256) {
    float s = 0.f;
#pragma unroll
    for (int sl = 0; sl < SHG; ++sl) s += hgp[((long)sl * B_ + b) * KA_ + i];
    hgs[i] = s; whs[i] = w_h[i];
  }
  __syncthreads();
  for (int l = wv; l < L_; l += 4) {
    const float* sp = sp_proj + ((long)b * L_ + l) * KA_;
    float s = 0.f;
    for (int k = lane; k < KA_; k += 64) s += whs[k] * tanhf(sp[k] + hgs[k]);
#pragma unroll
    for (int off = 32; off > 0; off >>= 1) s += __shfl_down(s, off);
    if (lane == 0) zs[l] = s;
  }
  __syncthreads();
  if (wv == 0) {
    float v = (lane < L_) ? zs[lane] : -INFINITY;
    float mx = v;
#pragma unroll
    for (int off = 32; off > 0; off >>= 1) mx = fmaxf(mx, __shfl_xor(mx, off));
    float e = (lane < L_) ? expf(v - mx) : 0.f;
    float sum = e;
#pragma unroll
    for (int off = 32; off > 0; off >>= 1) sum += __shfl_xor(sum, off);
    if (lane < L_) alph[lane] = e / sum;
  }
  __syncthreads();
  const int d4 = half * 256 + tid;
  const float4* h4 = (const float4*)h;
  const float4* sp4 = (const float4*)spatial;
  float4 acc = h4[(long)b * 512 + d4];
#pragma unroll 7
  for (int l = 0; l < L_; ++l) {
    const float w = alph[l];
    const float4 v = sp4[((long)b * L_ + l) * 512 + d4];
    acc.x = fmaf(w, v.x, acc.x); acc.y = fmaf(w, v.y, acc.y);
    acc.z = fmaf(w, v.z, acc.z); acc.w = fmaf(w, v.w, acc.w);
  }
  short4 hv, lv;
  split1(acc.x, &hv.x, &lv.x); split1(acc.y, &hv.y, &lv.y);
  split1(acc.z, &hv.z, &lv.z); split1(acc.w, &hv.w, &lv.w);
  *(short4*)&a_hi[(long)b * D_ + d4*4] = hv;
  *(short4*)&a_lo[(long)b * D_ + d4*4] = lv;
}

template<int S, bool GATHER>
__global__ __launch_bounds__(256)
void logits_argmax_k(const float* __restrict__ lp, const float* __restrict__ bias,
                     float* __restrict__ outL, int* __restrict__ tok,
                     float* __restrict__ tokout,
                     const float* __restrict__ embed,
                     const short* __restrict__ h_hi, const short* __restrict__ h_lo,
                     short* __restrict__ xh_hi, short* __restrict__ xh_lo)
{
  const int b = blockIdx.x, tid = threadIdx.x;
  float bv = -INFINITY; int bi = 0x7fffffff;
  for (int j = tid; j < V_; j += 256) {
    float v = bias[j];
#pragma unroll
    for (int sl = 0; sl < S; ++sl) v += lp[((long)sl * B_ + b) * VP_ + j];
    outL[(long)b * (T_*V_) + j] = v;
    if (v > bv) { bv = v; bi = j; }
  }
  __shared__ float sv[256];
  __shared__ int   si[256];
  sv[tid] = bv; si[tid] = bi;
  __syncthreads();
  for (int s = 128; s > 0; s >>= 1) {
    if (tid < s) {
      const float ov = sv[tid + s]; const int oi = si[tid + s];
      if (ov > sv[tid] || (ov == sv[tid] && oi < si[tid])) { sv[tid] = ov; si[tid] = oi; }
    }
    __syncthreads();
  }
  if (tid == 0) { tok[b] = si[0]; tokout[(long)b * T_] = (float)si[0]; }
  if (GATHER) {
    __syncthreads();
    const int tk = si[0];
    short* rh = xh_hi + (long)b * KT2_;
    short* rl = xh_lo + (long)b * KT2_;
    const float* e = embed + (long)tk * E_;
    for (int i = tid; i < E_; i += 256) split1(e[i], &rh[i], &rl[i]);
    for (int i = tid; i < H_; i += 256) { rh[E_+i] = h_hi[(long)b*H_ + i]; rl[E_+i] = h_lo[(long)b*H_ + i]; }
  }
}

// ============ host ============
extern "C" void kernel_launch(void* const* d_in, const int* in_sizes, int n_in,
                              void* d_out, int out_size, void* d_ws, size_t ws_size,
                              hipStream_t stream)
{
  const float* spatial  = (const float*)d_in[0];
  const float* global_  = (const float*)d_in[1];
  const float* embed    = (const float*)d_in[2];
  const float* W_ih     = (const float*)d_in[3];
  const float* W_hh     = (const float*)d_in[4];
  const float* b_ih     = (const float*)d_in[5];
  const float* b_hh     = (const float*)d_in[6];
  const float* W_v      = (const float*)d_in[7];
  const float* W_g      = (const float*)d_in[8];
  const float* w_h      = (const float*)d_in[9];
  const float* W_p_w    = (const float*)d_in[10];
  const float* W_p_b    = (const float*)d_in[11];
  const float* W_init_h = (const float*)d_in[12];
  const float* W_init_m = (const float*)d_in[13];
  float* out = (float*)d_out;
  float* tokout = out + (long)B_ * T_ * V_;

  char* base = (char*)d_ws;
  const size_t NEED_PRE = 284983808;
  const size_t NEED_FB  = 62390784;
  if (ws_size < NEED_FB) return;

  if (ws_size >= NEED_PRE) {
    float* sp      = (float*)(base + 0);           // 12,845,056
    float* h       = (float*)(base + 12845056);    //  1,048,576
    float* m       = (float*)(base + 13893632);    //  1,048,576
    short* h_hi    = (short*)(base + 14942208);    //    524,288
    short* h_lo    = (short*)(base + 15466496);
    short* a_hi    = (short*)(base + 15990784);
    short* a_lo    = (short*)(base + 16515072);
    short* xh_hi   = (short*)(base + 17039360);    //    655,360
    short* xh_lo   = (short*)(base + 17694720);
    short* g_hi    = (short*)(base + 18350080);    //    524,288
    short* g_lo    = (short*)(base + 18874368);
    float* gconst  = (float*)(base + 19398656);    //  4,194,304
    int*   tok     = (int*)  (base + 23592960);    //        512
    float* arena   = (float*)(base + 23593472);    // 83,886,080
    short* Wcat_hi = (short*)(base + 107479552);   // 41,943,040 (8192 x 2560)
    short* Wcat_lo = (short*)(base + 149422592);
    short* Wp_hi   = (short*)(base + 191365632);   // 41,418,752 (10112 x 2048)
    short* Wp_lo   = (short*)(base + 232784384);
    short* WvT_hi  = (short*)(base + 274203136);   //  2,097,152
    short* WvT_lo  = (short*)(base + 276300288);
    short* WgT_hi  = (short*)(base + 278397440);
    short* WgT_lo  = (short*)(base + 280494592);
    float* hg      = (float*)(base + 282591744);   //    262,144
    float* zbuf    = (float*)(base + 282853888);   //     32,768
    float* cpart   = (float*)(base + 282886656);   //  2,097,152
    // end: 284,983,808

    init_tok_k<<<1, 128, 0, stream>>>(tok);
    split_plane_k<<<256, 256, 0, stream>>>(global_, (long)B_*D_, g_hi, g_lo);

    // ---- sp = spatial @ W_v (S=4, k_len=512) ----
    split_t_k<<<dim3(KA_/64, D_/64), 256, 0, stream>>>(W_v, D_, KA_, WvT_hi, WvT_lo);
    short* spA_hi = Wp_hi;
    short* spA_lo = (short*)((char*)Wp_hi + 25690112);
    split_plane_k<<<12544, 256, 0, stream>>>(spatial, (long)B_*L_*D_, spA_hi, spA_lo);
    float* sppart = (float*)Wcat_hi;
    gemm_lds<<<dim3(4, 4, 49), 256, 0, stream>>>(
        spA_hi, spA_lo, D_, WvT_hi, WvT_lo, D_, sppart, B_*L_, KA_, 512);
    reduce_sp_k<<<3136, 256, 0, stream>>>((const float4*)sppart, (float4*)sp);

    // ---- gconst = global_ @ W_ih[:,512:]^T + b_ih + b_hh ----
    short* Wglob_hi = Wp_hi;
    short* Wglob_lo = (short*)((char*)Wp_hi + 33554432);
    split_nt_k<<<dim3(2, H4_), 256, 0, stream>>>(W_ih + 512, ED_, H4_, D_, Wglob_hi, Wglob_lo, D_, 0);
    gemm_lds<<<dim3(64, 8, 1), 256, 0, stream>>>(
        g_hi, g_lo, D_, Wglob_hi, Wglob_lo, D_, arena, B_, H4_, 256);
    gred_k<<<(B_*H4_)/256, 256, 0, stream>>>(arena, b_ih, b_hh, gconst);

    // ---- loop weight planes ----
    split_nt_k<<<dim3(1, H4_), 256, 0, stream>>>(W_ih, ED_, H4_, E_, Wcat_hi, Wcat_lo, KT2_, 0);
    split_nt_k<<<dim3(2, H4_), 256, 0, stream>>>(W_hh, H_, H4_, H_, Wcat_hi, Wcat_lo, KT2_, E_);
    split_nt_k<<<dim3(2, VP_), 256, 0, stream>>>(W_p_w, H_, V_, H_, Wp_hi, Wp_lo, H_, 0);
    split_t_k<<<dim3(KA_/64, H_/64), 256, 0, stream>>>(W_g, H_, KA_, WgT_hi, WgT_lo);

    // ---- h0/m0 (S=16, k_len=128) ----
    {
      short* WTh = (short*)arena;
      short* WTl = (short*)((char*)arena + 8388608);
      float* prt = (float*)((char*)arena + 16777216);
      split_t_k<<<dim3(H_/64, D_/64), 256, 0, stream>>>(W_init_h, D_, H_, WTh, WTl);
      gemm_lds<<<dim3(16, 16, 1), 256, 0, stream>>>(
          g_hi, g_lo, D_, WTh, WTl, D_, prt, B_, H_, 128);
      reduce_tanh_k<<<(B_*H_)/256, 256, 0, stream>>>(prt, 16, h, h_hi, h_lo);
      split_t_k<<<dim3(H_/64, D_/64), 256, 0, stream>>>(W_init_m, D_, H_, WTh, WTl);
      gemm_lds<<<dim3(16, 16, 1), 256, 0, stream>>>(
          g_hi, g_lo, D_, WTh, WTl, D_, prt, B_, H_, 128);
      reduce_tanh_k<<<(B_*H_)/256, 256, 0, stream>>>(prt, 16, m, nullptr, nullptr);
    }

    gather_xh2_k<<<B_, 256, 0, stream>>>(embed, h_hi, h_lo, tok, xh_hi, xh_lo);

    for (int t = 0; t < T_; ++t) {
      // gates: S=8, k_len=320 (K=2560)
      gemm_lds<<<dim3(64, 8, 1), 256, 0, stream>>>(
          xh_hi, xh_lo, KT2_, Wcat_hi, Wcat_lo, KT2_, arena, B_, H4_, 320);
      lstm_reduce_k<8><<<(B_*H_)/256, 256, 0, stream>>>(
          arena, gconst, nullptr, nullptr, h, m, h_hi, h_lo);
      // hg: S=32, k_len=64
      gemm_lds<<<dim3(4, 32, 1), 256, 0, stream>>>(
          h_hi, h_lo, H_, WgT_hi, WgT_lo, H_, arena, B_, KA_, 64);
      // attention pipeline
      hgred_k<<<(B_*KA_)/256, 256, 0, stream>>>(arena, hg);
      z_k<<<(B_*L_)/4, 256, 0, stream>>>(sp, hg, w_h, zbuf);
      c_k<<<dim3(B_, 4), 256, 0, stream>>>(zbuf, spatial, cpart);
      comb_k<<<(B_*D_)/1024, 256, 0, stream>>>(cpart, h, a_hi, a_lo);
      // logits: S=8, k_len=256
      gemm_lds<<<dim3(79, 8, 1), 256, 0, stream>>>(
          a_hi, a_lo, H_, Wp_hi, Wp_lo, H_, arena, B_, VP_, 256);
      logits_argmax_k<8,true><<<B_, 256, 0, stream>>>(
          arena, W_p_b, out + (long)t * V_, tok, tokout + t,
          embed, h_hi, h_lo, xh_hi, xh_lo);
    }
  } else {
    // -------- fallback: fp32 weights, on-the-fly split --------
    float* sp    = (float*)(base + 0);
    float* WvTf  = (float*)(base + 12845056);
    float* WgTf  = (float*)(base + 17039360);
    float* h     = (float*)(base + 21233664);
    float* m     = (float*)(base + 22282240);
    short* h_hi  = (short*)(base + 24379392);
    short* h_lo  = (short*)(base + 24903680);
    short* a_hi  = (short*)(base + 25427968);
    short* a_lo  = (short*)(base + 25952256);
    short* xh_hi = (short*)(base + 26476544);
    short* xh_lo = (short*)(base + 27656192);
    int*   tok   = (int*)  (base + 28835840);
    float* arena = (float*)(base + 28836352);

    init_tok_k<<<1, 128, 0, stream>>>(tok);
    transpose_f32<<<dim3(KA_/64, D_/64), 256, 0, stream>>>(W_v, D_, KA_, WvTf);
    gemm_mfma<true><<<dim3(4, 1, 49), 256, 0, stream>>>(
        spatial, nullptr, D_, WvTf, D_, nullptr, 0, 1<<30, sp, B_*L_, KA_, KA_, D_);
    transpose_f32<<<dim3(KA_/64, H_/64), 256, 0, stream>>>(W_g, H_, KA_, WgTf);
    {
      float* WT  = arena;
      float* prt = (float*)((char*)arena + 16777216);
      transpose_f32<<<dim3(H_/64, D_/64), 256, 0, stream>>>(W_init_h, D_, H_, WT);
      gemm_mfma<true><<<dim3(16, 4, 1), 256, 0, stream>>>(
          global_, nullptr, D_, WT, D_, nullptr, 0, 1<<30, prt, B_, H_, H_, 512);
      reduce_tanh_k<<<(B_*H_)/256, 256, 0, stream>>>(prt, 4, h, h_hi, h_lo);
      transpose_f32<<<dim3(H_/64, D_/64), 256, 0, stream>>>(W_init_m, D_, H_, WT);
      gemm_mfma<true><<<dim3(16, 4, 1), 256, 0, stream>>>(
          global_, nullptr, D_, WT, D_, nullptr, 0, 1<<30, prt, B_, H_, H_, 512);
      reduce_tanh_k<<<(B_*H_)/256, 256, 0, stream>>>(prt, 4, m, nullptr, nullptr);
    }
    for (int t = 0; t < T_; ++t) {
      gather_xh_k<<<B_, 256, 0, stream>>>(embed, global_, h_hi, h_lo, tok, xh_hi, xh_lo);
      gemm_mfma<false><<<dim3(64, 8, 1), 256, 0, stream>>>(
          xh_hi, xh_lo, KT_, W_ih, ED_, W_hh, H_, ED_, arena, B_, H4_, H4_, 576);
      lstm_reduce_k<8><<<(B_*H_)/256, 256, 0, stream>>>(
          arena, nullptr, b_ih, b_hh, h, m, h_hi, h_lo);
      gemm_mfma<false><<<dim3(4, 16, 1), 256, 0, stream>>>(
          h_hi, h_lo, H_, WgTf, H_, nullptr, 0, 1<<30, arena, B_, KA_, KA_, 128);
      attn_k<16><<<dim3(B_, 2), 256, 0, stream>>>(sp, arena, w_h, spatial, h, a_hi, a_lo);
      gemm_mfma<false><<<dim3(79, 4, 1), 256, 0, stream>>>(
          a_hi, a_lo, H_, W_p_w, H_, nullptr, 0, 1<<30, arena, B_, VP_, V_, 512);
      logits_argmax_k<4,false><<<B_, 256, 0, stream>>>(
          arena, W_p_b, out + (long)t * V_, tok, tokout + t,
          nullptr, nullptr, nullptr, nullptr, nullptr);
    }
  }
}